// Round 1
// baseline (1152.735 us; speedup 1.0000x reference)
//
#include <hip/hip_runtime.h>
#include <hip/hip_bf16.h>

// Problem constants (fixed by setup_inputs)
// B=2048, L=64, V=4096, D=64, H=8, P=62

__device__ __forceinline__ unsigned short f2bf(float f) {
    union { float f; unsigned int i; } c; c.f = f;
    unsigned int i = c.i;
    unsigned int r = (i + 0x7fffu + ((i >> 16) & 1u)) >> 16;
    return (unsigned short)r;
}
__device__ __forceinline__ float asf(unsigned int u) {
    union { unsigned int i; float f; } c; c.i = u; return c.f;
}

__device__ __forceinline__ void fma4x8(float acc[4][8], float4 a, float4 b0, float4 b1) {
    float aa[4] = {a.x, a.y, a.z, a.w};
    float bb[8] = {b0.x, b0.y, b0.z, b0.w, b1.x, b1.y, b1.z, b1.w};
#pragma unroll
    for (int i = 0; i < 4; ++i)
#pragma unroll
        for (int j = 0; j < 8; ++j)
            acc[i][j] = fmaf(aa[i], bb[j], acc[i][j]);
}

// ---------------------------------------------------------------------------
// Kernel A: qkv table = W_emb (4096x64) @ W_qkv^T (64x1536) -> (4096x1536)
// grid 64*24 blocks, 256 threads, 64x64 tile, 4x4 per thread
// ---------------------------------------------------------------------------
__global__ __launch_bounds__(256) void k_qkv(const float* __restrict__ W_emb,
                                             const float* __restrict__ W_qkv,
                                             float* __restrict__ qkv) {
    __shared__ float At[4096]; // embT[c][tok]
    __shared__ float Bt[4096]; // WqT[c][r]
    int t = threadIdx.x;
    int bt = blockIdx.x / 24, rt = blockIdx.x - bt * 24;
    int r = t >> 2, part = t & 3;
    const float4* esrc = (const float4*)(W_emb + (size_t)((bt << 6) + r) * 64 + part * 16);
    const float4* wsrc = (const float4*)(W_qkv + (size_t)((rt << 6) + r) * 64 + part * 16);
#pragma unroll
    for (int j = 0; j < 4; ++j) {
        float4 e4 = esrc[j], w4 = wsrc[j];
        int c0 = part * 16 + j * 4;
        At[(c0 + 0) * 64 + r] = e4.x; At[(c0 + 1) * 64 + r] = e4.y;
        At[(c0 + 2) * 64 + r] = e4.z; At[(c0 + 3) * 64 + r] = e4.w;
        Bt[(c0 + 0) * 64 + r] = w4.x; Bt[(c0 + 1) * 64 + r] = w4.y;
        Bt[(c0 + 2) * 64 + r] = w4.z; Bt[(c0 + 3) * 64 + r] = w4.w;
    }
    __syncthreads();
    int l0 = (t >> 4) << 2, m0 = (t & 15) << 2;
    float acc[4][4] = {};
#pragma unroll 4
    for (int k = 0; k < 64; ++k) {
        float4 a  = *(const float4*)(At + k * 64 + l0);
        float4 bb = *(const float4*)(Bt + k * 64 + m0);
        float aa[4] = {a.x, a.y, a.z, a.w};
        float bv[4] = {bb.x, bb.y, bb.z, bb.w};
#pragma unroll
        for (int i = 0; i < 4; ++i)
#pragma unroll
            for (int j = 0; j < 4; ++j)
                acc[i][j] = fmaf(aa[i], bv[j], acc[i][j]);
    }
#pragma unroll
    for (int i = 0; i < 4; ++i) {
        float4 o4 = make_float4(acc[i][0], acc[i][1], acc[i][2], acc[i][3]);
        *(float4*)(qkv + (size_t)((bt << 6) + l0 + i) * 1536 + (rt << 6) + m0) = o4;
    }
}

// ---------------------------------------------------------------------------
// Kernel B: cs table cs[f][m], f<31: cos((f+1)*2pi/63*m), f in [31,62): sin(...)
// stored 62x64. grid 1 block, 256 threads.
// ---------------------------------------------------------------------------
__global__ void k_cs(float* __restrict__ cs) {
    int t = threadIdx.x;
    const float w = 6.283185307179586f / 63.0f;
    for (int e = t; e < 3968; e += 256) {
        int f = e >> 6, m = e & 63;
        float val;
        if (f < 31) {
            int r = ((f + 1) * m) % 63;
            val = cosf(w * (float)r);
        } else {
            int ff = f - 31;
            int r = ((ff + 1) * m) % 63;
            val = sinf(w * (float)r);
        }
        cs[e] = val;
    }
}

// ---------------------------------------------------------------------------
// Kernel C: fused attention per (b,h). 128 threads, 64KB LDS in 4 x 16KB bufs.
//   R0: qT -> scT -> attnT
//   R1: kT -> PWT -> UWT (in place) -> out
//   R2: WposT -> v
//   R3: CS -> finalsim
// ---------------------------------------------------------------------------
__global__ __launch_bounds__(128) void k_attn(const int* __restrict__ inputs,
                                              const float* __restrict__ qkv,
                                              const float* __restrict__ cs,
                                              const float* __restrict__ W_pos,
                                              const float* __restrict__ ln_g,
                                              const float* __restrict__ ln_b,
                                              __hip_bfloat16* __restrict__ out_n) {
    __shared__ float S[16384]; // exactly 64 KB
    float* R0 = S;
    float* R1 = S + 4096;
    float* R2 = S + 8192;
    float* R3 = S + 12288;
    int t = threadIdx.x;
    int b = blockIdx.x >> 3, h = blockIdx.x & 7;
    const int* toks = inputs + b * 64;

    // ---- P0: gather qT,kT ; load WposT ; copy CS ----
    {
        int r = t >> 1, part = t & 1;
        int tok = toks[r];
        const float4* qsrc = (const float4*)(qkv + (size_t)tok * 1536 + h * 64 + part * 32);
        const float4* ksrc = (const float4*)(qkv + (size_t)tok * 1536 + 512 + h * 64 + part * 32);
#pragma unroll
        for (int j = 0; j < 8; ++j) {
            float4 q4 = qsrc[j], k4 = ksrc[j];
            int c0 = part * 32 + j * 4;
            R0[(c0 + 0) * 64 + r] = q4.x; R0[(c0 + 1) * 64 + r] = q4.y;
            R0[(c0 + 2) * 64 + r] = q4.z; R0[(c0 + 3) * 64 + r] = q4.w;
            R1[(c0 + 0) * 64 + r] = k4.x; R1[(c0 + 1) * 64 + r] = k4.y;
            R1[(c0 + 2) * 64 + r] = k4.z; R1[(c0 + 3) * 64 + r] = k4.w;
        }
        int p = t & 63, quarter = t >> 6; // 0..1
        for (int i = 0; i < 32; ++i) {
            int mp = quarter * 32 + i;
            R2[mp * 64 + p] = (p < 62) ? W_pos[p * 64 + mp] : 0.0f;
        }
        for (int i = t; i < 992; i += 128)
            ((float4*)R3)[i] = ((const float4*)cs)[i];
    }
    __syncthreads();

    int l0 = (t >> 3) << 2;       // 0..60
    int m0 = (t & 7) << 3;        // 0..56

    // ---- GEMM1: sim = qT^T * kT ----
    float acc[4][8] = {};
#pragma unroll 2
    for (int k = 0; k < 64; ++k) {
        float4 a  = *(const float4*)(R0 + k * 64 + l0);
        float4 b0 = *(const float4*)(R1 + k * 64 + m0);
        float4 b1 = *(const float4*)(R1 + k * 64 + m0 + 4);
        fma4x8(acc, a, b0, b1);
    }
    __syncthreads();
    // sim epilogue: scale 1/8, clip masked to 0, store scT[m][l] into R0
    {
        int tokm[8];
#pragma unroll
        for (int j = 0; j < 8; ++j) tokm[j] = toks[m0 + j];
#pragma unroll
        for (int j = 0; j < 8; ++j) {
            bool msk = (tokm[j] == 0);
            float4 o;
            o.x = msk ? 0.0f : acc[0][j] * 0.125f;
            o.y = msk ? 0.0f : acc[1][j] * 0.125f;
            o.z = msk ? 0.0f : acc[2][j] * 0.125f;
            o.w = msk ? 0.0f : acc[3][j] * 0.125f;
            *(float4*)(R0 + (m0 + j) * 64 + l0) = o;
        }
    }
    __syncthreads();

    // ---- GEMM2: PW = scT^T * WposT -> PWT[p][l] in R1 ----
    float acc2[4][8] = {};
#pragma unroll 2
    for (int k = 0; k < 64; ++k) {
        float4 a  = *(const float4*)(R0 + k * 64 + l0);
        float4 b0 = *(const float4*)(R2 + k * 64 + m0);
        float4 b1 = *(const float4*)(R2 + k * 64 + m0 + 4);
        fma4x8(acc2, a, b0, b1);
    }
#pragma unroll
    for (int j = 0; j < 8; ++j) {
        float4 o = make_float4(acc2[0][j], acc2[1][j], acc2[2][j], acc2[3][j]);
        *(float4*)(R1 + (m0 + j) * 64 + l0) = o;
    }
    __syncthreads();

    // ---- P2.5: v gather into R2 + twist PWT -> UWT in place in R1 ----
    {
        int r = t >> 1, part = t & 1;
        int tok = toks[r];
        const float4* vsrc = (const float4*)(qkv + (size_t)tok * 1536 + 1024 + h * 64 + part * 32);
        float4 v4[8];
#pragma unroll
        for (int j = 0; j < 8; ++j) v4[j] = vsrc[j];
        // twist: e = f*64+l, f in [0,31)
        for (int e = t; e < 1984; e += 128) {
            float pwc = R1[e];
            float pws = R1[e + 1984];
            float c = R3[e], s = R3[e + 1984];
            R1[e]        = fmaf(pwc, c, -pws * s);
            R1[e + 1984] = fmaf(pwc, s,  pws * c);
        }
#pragma unroll
        for (int j = 0; j < 8; ++j)
            *(float4*)(R2 + r * 64 + part * 32 + j * 4) = v4[j];
    }
    __syncthreads();

    // ---- GEMM3: bias = UWT^T * CS (K=62), final = scT + bias/62 -> R3 ----
    float acc3[4][8] = {};
#pragma unroll 2
    for (int k = 0; k < 62; ++k) {
        float4 a  = *(const float4*)(R1 + k * 64 + l0);
        float4 b0 = *(const float4*)(R3 + k * 64 + m0);
        float4 b1 = *(const float4*)(R3 + k * 64 + m0 + 4);
        fma4x8(acc3, a, b0, b1);
    }
    __syncthreads(); // all CS reads done before overwriting R3
    {
        float fin[4][8];
#pragma unroll
        for (int j = 0; j < 8; ++j) {
            float4 s4 = *(const float4*)(R0 + (m0 + j) * 64 + l0);
            fin[0][j] = fmaf(acc3[0][j], 1.0f / 62.0f, s4.x);
            fin[1][j] = fmaf(acc3[1][j], 1.0f / 62.0f, s4.y);
            fin[2][j] = fmaf(acc3[2][j], 1.0f / 62.0f, s4.z);
            fin[3][j] = fmaf(acc3[3][j], 1.0f / 62.0f, s4.w);
        }
#pragma unroll
        for (int i = 0; i < 4; ++i) {
            *(float4*)(R3 + (l0 + i) * 64 + m0)     = make_float4(fin[i][0], fin[i][1], fin[i][2], fin[i][3]);
            *(float4*)(R3 + (l0 + i) * 64 + m0 + 4) = make_float4(fin[i][4], fin[i][5], fin[i][6], fin[i][7]);
        }
    }
    __syncthreads();

    // ---- P4: softmax rows of R3 -> attnT[m][l] in R0 (2 threads per row) ----
    {
        int l = t >> 1, q = t & 1;
        float x[32];
        const float4* rowv = (const float4*)(R3 + l * 64 + q * 32);
#pragma unroll
        for (int j = 0; j < 8; ++j) {
            float4 v = rowv[j];
            x[j * 4 + 0] = v.x; x[j * 4 + 1] = v.y; x[j * 4 + 2] = v.z; x[j * 4 + 3] = v.w;
        }
#pragma unroll
        for (int i = 0; i < 32; ++i) {
            int m = q * 32 + i;
            if (toks[m] == 0) x[i] = -1e9f;
        }
        float mx = -3e38f;
#pragma unroll
        for (int i = 0; i < 32; ++i) mx = fmaxf(mx, x[i]);
        mx = fmaxf(mx, __shfl_xor(mx, 1));
        float s = 0.0f;
#pragma unroll
        for (int i = 0; i < 32; ++i) { x[i] = expf(x[i] - mx); s += x[i]; }
        s += __shfl_xor(s, 1);
        float inv = 1.0f / s;
#pragma unroll
        for (int i = 0; i < 32; ++i)
            R0[(q * 32 + i) * 64 + l] = x[i] * inv;
    }
    __syncthreads();

    // ---- GEMM4: out = attnT^T * v -> R1[l][d] ----
    float acc4[4][8] = {};
#pragma unroll 2
    for (int k = 0; k < 64; ++k) {
        float4 a  = *(const float4*)(R0 + k * 64 + l0);
        float4 b0 = *(const float4*)(R2 + k * 64 + m0);
        float4 b1 = *(const float4*)(R2 + k * 64 + m0 + 4);
        fma4x8(acc4, a, b0, b1);
    }
#pragma unroll
    for (int i = 0; i < 4; ++i) {
        *(float4*)(R1 + (l0 + i) * 64 + m0)     = make_float4(acc4[i][0], acc4[i][1], acc4[i][2], acc4[i][3]);
        *(float4*)(R1 + (l0 + i) * 64 + m0 + 4) = make_float4(acc4[i][4], acc4[i][5], acc4[i][6], acc4[i][7]);
    }
    __syncthreads();

    // ---- P6: LayerNorm per row over d, write bf16 out_n[b][h][l][d] ----
    {
        int l = t >> 1, q = t & 1;
        float x[32];
        const float4* rowv = (const float4*)(R1 + l * 64 + q * 32);
#pragma unroll
        for (int j = 0; j < 8; ++j) {
            float4 v = rowv[j];
            x[j * 4 + 0] = v.x; x[j * 4 + 1] = v.y; x[j * 4 + 2] = v.z; x[j * 4 + 3] = v.w;
        }
        float s1 = 0.0f, s2 = 0.0f;
#pragma unroll
        for (int i = 0; i < 32; ++i) { s1 += x[i]; s2 = fmaf(x[i], x[i], s2); }
        s1 += __shfl_xor(s1, 1);
        s2 += __shfl_xor(s2, 1);
        float mu = s1 * (1.0f / 64.0f);
        float var = s2 * (1.0f / 64.0f) - mu * mu;
        float rstd = rsqrtf(var + 1e-5f);
        unsigned int pk[16];
#pragma unroll
        for (int i = 0; i < 32; i += 2) {
            int d = q * 32 + i;
            float y0 = (x[i]     - mu) * rstd * ln_g[d]     + ln_b[d];
            float y1 = (x[i + 1] - mu) * rstd * ln_g[d + 1] + ln_b[d + 1];
            pk[i >> 1] = (unsigned int)f2bf(y0) | ((unsigned int)f2bf(y1) << 16);
        }
        unsigned int* dst = (unsigned int*)(out_n + ((((size_t)b * 8 + h) * 64 + l) * 64 + q * 32));
#pragma unroll
        for (int j = 0; j < 4; ++j)
            ((uint4*)dst)[j] = make_uint4(pk[j * 4 + 0], pk[j * 4 + 1], pk[j * 4 + 2], pk[j * 4 + 3]);
    }
}

// ---------------------------------------------------------------------------
// Kernel D: per b: h1 = relu(ft @ W1^T + b1), g[b,d,o] = sum_l w_l * h1
// block per b, 256 threads. ft staged per 16-l chunk.
// ---------------------------------------------------------------------------
__global__ __launch_bounds__(256) void k_mlp(const int* __restrict__ inputs,
                                             const __hip_bfloat16* __restrict__ out_n,
                                             const float* __restrict__ W1,
                                             const float* __restrict__ b1,
                                             float* __restrict__ gws) {
    __shared__ float ft[8704];      // [8h][16l][68] padded
    __shared__ float w1T[8][64];    // w1T[h][o]
    __shared__ float b1s[64];
    __shared__ float wl[64];
    int t = threadIdx.x;
    int b = blockIdx.x;
    if (t < 64) b1s[t] = b1[t];
    for (int e = t; e < 512; e += 256) {
        int o = e >> 3, hh = e & 7;
        w1T[hh][o] = W1[e]; // W1[o][h], e = o*8+h
    }
    if (t < 64) {
        int tok = inputs[b * 64 + t];
        unsigned long long bal = __ballot(tok != 0);
        int cnt = __popcll(bal);
        float Minv = (cnt > 0) ? (1.0f / (float)cnt) : 0.0f;
        wl[t] = (tok != 0) ? Minv : 0.0f;
    }
    float g4[4][4] = {};
    int d0 = (t >> 4) << 2, o0 = (t & 15) << 2;
    for (int lc = 0; lc < 4; ++lc) {
        __syncthreads();
        {
            int row = t >> 1, half = t & 1;
            int hh = row >> 4, l = row & 15;
            const uint4* src = (const uint4*)((const unsigned short*)out_n +
                ((((size_t)b * 8 + hh) * 64 + lc * 16 + l) * 64 + half * 32));
            float* dst = ft + (hh * 16 + l) * 68 + half * 32;
#pragma unroll
            for (int j = 0; j < 4; ++j) {
                uint4 u = src[j];
                dst[j * 8 + 0] = asf(u.x << 16); dst[j * 8 + 1] = asf(u.x & 0xffff0000u);
                dst[j * 8 + 2] = asf(u.y << 16); dst[j * 8 + 3] = asf(u.y & 0xffff0000u);
                dst[j * 8 + 4] = asf(u.z << 16); dst[j * 8 + 5] = asf(u.z & 0xffff0000u);
                dst[j * 8 + 6] = asf(u.w << 16); dst[j * 8 + 7] = asf(u.w & 0xffff0000u);
            }
        }
        __syncthreads();
        for (int l = 0; l < 16; ++l) {
            float pre[4][4];
#pragma unroll
            for (int j = 0; j < 4; ++j) {
                float bv = b1s[o0 + j];
                pre[0][j] = bv; pre[1][j] = bv; pre[2][j] = bv; pre[3][j] = bv;
            }
#pragma unroll
            for (int hh = 0; hh < 8; ++hh) {
                float4 av = *(const float4*)(ft + (hh * 16 + l) * 68 + d0);
                float4 wv = *(const float4*)(&w1T[hh][o0]);
                float aa[4] = {av.x, av.y, av.z, av.w};
                float ww[4] = {wv.x, wv.y, wv.z, wv.w};
#pragma unroll
                for (int i = 0; i < 4; ++i)
#pragma unroll
                    for (int j = 0; j < 4; ++j)
                        pre[i][j] = fmaf(aa[i], ww[j], pre[i][j]);
            }
            float w = wl[lc * 16 + l];
#pragma unroll
            for (int i = 0; i < 4; ++i)
#pragma unroll
                for (int j = 0; j < 4; ++j)
                    g4[i][j] = fmaf(w, fmaxf(pre[i][j], 0.0f), g4[i][j]);
        }
    }
#pragma unroll
    for (int i = 0; i < 4; ++i) {
        float4 o4 = make_float4(g4[i][0], g4[i][1], g4[i][2], g4[i][3]);
        *(float4*)(gws + ((size_t)b * 64 + d0 + i) * 64 + o0) = o4;
    }
}

// ---------------------------------------------------------------------------
// Kernel E: per name n: gbar = mean over 4 words of g; out = W2 @ gbar + b2
// grid 512 blocks, 256 threads.
// ---------------------------------------------------------------------------
__global__ __launch_bounds__(256) void k_final(const float* __restrict__ gws,
                                               const float* __restrict__ W2,
                                               const float* __restrict__ b2,
                                               float* __restrict__ out) {
    __shared__ float gbar[4096];
    __shared__ float w2s[32 * 68];
    __shared__ float b2s[32];
    int t = threadIdx.x;
    int n = blockIdx.x;
    for (int e = t; e < 4096; e += 256) {
        size_t base = (size_t)(4 * n) * 4096 + e;
        gbar[e] = 0.25f * (gws[base] + gws[base + 4096] + gws[base + 8192] + gws[base + 12288]);
    }
    for (int e = t; e < 2048; e += 256) {
        int p = e >> 6, o = e & 63;
        w2s[p * 68 + o] = W2[e]; // W2[p][o]
    }
    if (t < 32) b2s[t] = b2[t];
    __syncthreads();
#pragma unroll
    for (int jj = 0; jj < 8; ++jj) {
        int f = jj * 256 + t;
        int d = f >> 5, p = f & 31;
        float acc = b2s[p];
        for (int o4 = 0; o4 < 16; ++o4) {
            float4 gv = *(const float4*)(gbar + d * 64 + o4 * 4);
            float4 wv = *(const float4*)(w2s + p * 68 + o4 * 4);
            acc = fmaf(gv.x, wv.x, acc);
            acc = fmaf(gv.y, wv.y, acc);
            acc = fmaf(gv.z, wv.z, acc);
            acc = fmaf(gv.w, wv.w, acc);
        }
        out[(size_t)n * 2048 + f] = acc;
    }
}

// ---------------------------------------------------------------------------
extern "C" void kernel_launch(void* const* d_in, const int* in_sizes, int n_in,
                              void* d_out, int out_size, void* d_ws, size_t ws_size,
                              hipStream_t stream) {
    const int*   inputs = (const int*)d_in[0];
    const float* W_emb  = (const float*)d_in[1];
    const float* W_qkv  = (const float*)d_in[2];
    const float* W_pos  = (const float*)d_in[3];
    const float* ln_g   = (const float*)d_in[4];
    const float* ln_b   = (const float*)d_in[5];
    const float* W1     = (const float*)d_in[6];
    const float* b1     = (const float*)d_in[7];
    const float* W2     = (const float*)d_in[8];
    const float* b2     = (const float*)d_in[9];
    float* out = (float*)d_out;

    // ws layout (floats): qkv 6291456 | cs 3968 | g 8388608 | out_n bf16 67108864
    float* qkv = (float*)d_ws;
    float* cs  = qkv + 6291456;
    float* gws = cs + 3968;
    __hip_bfloat16* out_n = (__hip_bfloat16*)(gws + 8388608);

    hipLaunchKernelGGL(k_qkv,   dim3(64 * 24), dim3(256), 0, stream, W_emb, W_qkv, qkv);
    hipLaunchKernelGGL(k_cs,    dim3(1),       dim3(256), 0, stream, cs);
    hipLaunchKernelGGL(k_attn,  dim3(16384),   dim3(128), 0, stream, inputs, qkv, cs, W_pos, ln_g, ln_b, out_n);
    hipLaunchKernelGGL(k_mlp,   dim3(2048),    dim3(256), 0, stream, inputs, out_n, W1, b1, gws);
    hipLaunchKernelGGL(k_final, dim3(512),     dim3(256), 0, stream, gws, W2, b2, out);
}

// Round 2
// 506.546 us; speedup vs baseline: 2.2757x; 2.2757x over previous
//
#include <hip/hip_runtime.h>
#include <hip/hip_bf16.h>

// Problem constants: B=2048, L=64, V=4096, D=64, H=8, P=62

typedef __attribute__((ext_vector_type(8))) short short8;
typedef __attribute__((ext_vector_type(4))) float f32x4;

union FragU { uint4 u; short8 v; };

__device__ __forceinline__ unsigned short f2bf(float f) {
    union { float f; unsigned int i; } c; c.f = f;
    unsigned int i = c.i;
    unsigned int r = (i + 0x7fffu + ((i >> 16) & 1u)) >> 16;
    return (unsigned short)r;
}
__device__ __forceinline__ float asf(unsigned int u) {
    union { unsigned int i; float f; } c; c.i = u; return c.f;
}
__device__ __forceinline__ float bfsel(uint2 g, int i) {
    unsigned u = (i < 2) ? g.x : g.y;
    return asf((i & 1) ? (u & 0xffff0000u) : (u << 16));
}

// xor-1 lane-pair pack: lane holds val[nt] for col 16*nt+c of row `rowptr`.
// Writes bf16 pairs: even lane writes nt=0,1; odd lane writes nt=2,3.
// rowptr is a dword pointer to the row (nt stride = 8 dwords = 16 bf16).
__device__ __forceinline__ void packstore4(unsigned* rowptr, int c,
                                           float v0, float v1, float v2, float v3) {
    float p0 = __shfl_xor(v0, 1), p1 = __shfl_xor(v1, 1);
    float p2 = __shfl_xor(v2, 1), p3 = __shfl_xor(v3, 1);
    int odd = c & 1;
    unsigned a0 = odd ? ((unsigned)f2bf(p2) | ((unsigned)f2bf(v2) << 16))
                      : ((unsigned)f2bf(v0) | ((unsigned)f2bf(p0) << 16));
    unsigned a1 = odd ? ((unsigned)f2bf(p3) | ((unsigned)f2bf(v3) << 16))
                      : ((unsigned)f2bf(v1) | ((unsigned)f2bf(p1) << 16));
    int ba = (c >> 1) + (odd ? 16 : 0);
    rowptr[ba] = a0; rowptr[ba + 8] = a1;
}

// ---------------------------------------------------------------------------
// Kernel A: qkv table = W_emb (4096x64) @ W_qkv^T -> bf16 (4096x1536)
// ---------------------------------------------------------------------------
__global__ __launch_bounds__(256) void k_qkv(const float* __restrict__ W_emb,
                                             const float* __restrict__ W_qkv,
                                             unsigned short* __restrict__ qkvb) {
    __shared__ float At[4096];
    __shared__ float Bt[4096];
    int t = threadIdx.x;
    int bt = blockIdx.x / 24, rt = blockIdx.x - bt * 24;
    int r = t >> 2, part = t & 3;
    const float4* esrc = (const float4*)(W_emb + (size_t)((bt << 6) + r) * 64 + part * 16);
    const float4* wsrc = (const float4*)(W_qkv + (size_t)((rt << 6) + r) * 64 + part * 16);
#pragma unroll
    for (int j = 0; j < 4; ++j) {
        float4 e4 = esrc[j], w4 = wsrc[j];
        int c0 = part * 16 + j * 4;
        At[(c0 + 0) * 64 + r] = e4.x; At[(c0 + 1) * 64 + r] = e4.y;
        At[(c0 + 2) * 64 + r] = e4.z; At[(c0 + 3) * 64 + r] = e4.w;
        Bt[(c0 + 0) * 64 + r] = w4.x; Bt[(c0 + 1) * 64 + r] = w4.y;
        Bt[(c0 + 2) * 64 + r] = w4.z; Bt[(c0 + 3) * 64 + r] = w4.w;
    }
    __syncthreads();
    int l0 = (t >> 4) << 2, m0 = (t & 15) << 2;
    float acc[4][4] = {};
#pragma unroll 4
    for (int k = 0; k < 64; ++k) {
        float4 a  = *(const float4*)(At + k * 64 + l0);
        float4 bb = *(const float4*)(Bt + k * 64 + m0);
        float aa[4] = {a.x, a.y, a.z, a.w};
        float bv[4] = {bb.x, bb.y, bb.z, bb.w};
#pragma unroll
        for (int i = 0; i < 4; ++i)
#pragma unroll
            for (int j = 0; j < 4; ++j)
                acc[i][j] = fmaf(aa[i], bv[j], acc[i][j]);
    }
#pragma unroll
    for (int i = 0; i < 4; ++i) {
        unsigned w0 = (unsigned)f2bf(acc[i][0]) | ((unsigned)f2bf(acc[i][1]) << 16);
        unsigned w1 = (unsigned)f2bf(acc[i][2]) | ((unsigned)f2bf(acc[i][3]) << 16);
        unsigned* dst = (unsigned*)(qkvb + (size_t)((bt << 6) + l0 + i) * 1536 + (rt << 6) + m0);
        dst[0] = w0; dst[1] = w1;
    }
}

// ---------------------------------------------------------------------------
// Kernel B: trig + W_pos tables, padded 64-col layout (cos j=0..30, 0, sin 32..62, 0)
//  cst[m][j] = trig_j(m)   (B of GEMM3: rows m, k=j contiguous)
//  csl[j][l] = trig_j(l)   (twist table: row j, l contiguous)
//  wpos[j][m]: j<=30 <- W_pos[j], j==31 0, 32..62 <- W_pos[j-1], 63 0
// ---------------------------------------------------------------------------
__global__ void k_tab(const float* __restrict__ W_pos,
                      unsigned short* __restrict__ cst,
                      unsigned short* __restrict__ csl,
                      unsigned short* __restrict__ wpos) {
    int t = threadIdx.x;
    const float w = 6.283185307179586f / 63.0f;
    for (int e = t; e < 4096; e += 256) {
        int row = e >> 6, col = e & 63;
        // cst: j = col, x = row
        {
            int j = col, x = row;
            float val = 0.0f;
            if (j < 31)       val = cosf(w * (float)(((j + 1) * x) % 63));
            else if (j >= 32 && j < 63) val = sinf(w * (float)(((j - 31) * x) % 63));
            cst[e] = f2bf(val);
        }
        // csl: j = row, x = col
        {
            int j = row, x = col;
            float val = 0.0f;
            if (j < 31)       val = cosf(w * (float)(((j + 1) * x) % 63));
            else if (j >= 32 && j < 63) val = sinf(w * (float)(((j - 31) * x) % 63));
            csl[e] = f2bf(val);
        }
        // wpos
        {
            int j = row;
            float val = 0.0f;
            if (j < 31) val = W_pos[j * 64 + col];
            else if (j >= 32 && j < 63) val = W_pos[(j - 1) * 64 + col];
            wpos[e] = f2bf(val);
        }
    }
}

// ---------------------------------------------------------------------------
// Kernel C: fused attention, MFMA, one wave per (b,h). Block = 2 waves.
// Per-wave LDS: 2 slots of 64 rows x 72 bf16 (= 2304 dwords each).
//   S0: Q -> SC -> ATTN      S1: K -> UW -> V^T
// ---------------------------------------------------------------------------
__global__ __launch_bounds__(128, 2) void k_attn(
    const int* __restrict__ inputs,
    const unsigned short* __restrict__ qkvb,
    const unsigned short* __restrict__ cstg,
    const unsigned short* __restrict__ cslg,
    const unsigned short* __restrict__ wposg,
    const float* __restrict__ ln_g,
    const float* __restrict__ ln_b,
    unsigned short* __restrict__ out_n)
{
    __shared__ __align__(16) unsigned int smem[9216]; // 2 waves * 2 slots * 2304 dw
    int t = threadIdx.x, w = t >> 6, lane = t & 63;
    unsigned int* S0d = smem + w * 4608;
    unsigned int* S1d = S0d + 2304;
    int task = blockIdx.x * 2 + w;
    int b = task >> 3, h = task & 7;
    const int* toks = inputs + b * 64;

    int r = lane & 15, q = lane >> 4, c = r;
    int tk = toks[lane];

    int mk[4]; float gv[4], bvv[4];
#pragma unroll
    for (int nt = 0; nt < 4; ++nt) {
        mk[nt] = (toks[16 * nt + c] == 0);
        gv[nt] = ln_g[16 * nt + c];
        bvv[nt] = ln_b[16 * nt + c];
    }

    // ---- gather Q -> S0, K -> S1 (lane = row, 128B each) ----
    {
        const uint4* qsrc = (const uint4*)(qkvb + (size_t)tk * 1536 + h * 64);
        const uint4* ksrc = (const uint4*)(qkvb + (size_t)tk * 1536 + 512 + h * 64);
        uint4* qdst = (uint4*)(S0d + lane * 36);
        uint4* kdst = (uint4*)(S1d + lane * 36);
#pragma unroll
        for (int j = 0; j < 8; ++j) { qdst[j] = qsrc[j]; kdst[j] = ksrc[j]; }
    }

    f32x4 acc[4][4];
    const f32x4 zf = {0.f, 0.f, 0.f, 0.f};

    // ---- GEMM1: sim = Q K^T (A=S0 rows l, B=S1 rows m) ----
#pragma unroll
    for (int mt = 0; mt < 4; ++mt)
#pragma unroll
        for (int nt = 0; nt < 4; ++nt) acc[mt][nt] = zf;
#pragma unroll
    for (int ks = 0; ks < 2; ++ks) {
        FragU Af[4], Bf[4];
#pragma unroll
        for (int mt = 0; mt < 4; ++mt)
            Af[mt].u = *(const uint4*)(S0d + (16 * mt + r) * 36 + 16 * ks + 4 * q);
#pragma unroll
        for (int nt = 0; nt < 4; ++nt)
            Bf[nt].u = *(const uint4*)(S1d + (16 * nt + r) * 36 + 16 * ks + 4 * q);
#pragma unroll
        for (int mt = 0; mt < 4; ++mt)
#pragma unroll
            for (int nt = 0; nt < 4; ++nt)
                acc[mt][nt] = __builtin_amdgcn_mfma_f32_16x16x32_bf16(Af[mt].v, Bf[nt].v, acc[mt][nt], 0, 0, 0);
    }
    // epilogue: scale 1/8, mask cols, pack bf16 SC -> S0
#pragma unroll
    for (int mt = 0; mt < 4; ++mt)
#pragma unroll
        for (int i = 0; i < 4; ++i) {
            int l = 16 * mt + 4 * q + i;
            float v0 = mk[0] ? 0.f : acc[mt][0][i] * 0.125f;
            float v1 = mk[1] ? 0.f : acc[mt][1][i] * 0.125f;
            float v2 = mk[2] ? 0.f : acc[mt][2][i] * 0.125f;
            float v3 = mk[3] ? 0.f : acc[mt][3][i] * 0.125f;
            packstore4(S0d + l * 36, c, v0, v1, v2, v3);
        }

    // ---- GEMM2: pos_w = SC @ Wpos^T (A=S0, B=wpos global) + in-reg twist -> UW in S1 ----
#pragma unroll
    for (int mt = 0; mt < 4; ++mt)
#pragma unroll
        for (int nt = 0; nt < 4; ++nt) acc[mt][nt] = zf;
#pragma unroll
    for (int ks = 0; ks < 2; ++ks) {
        FragU Af[4], Bf[4];
#pragma unroll
        for (int mt = 0; mt < 4; ++mt)
            Af[mt].u = *(const uint4*)(S0d + (16 * mt + r) * 36 + 16 * ks + 4 * q);
#pragma unroll
        for (int nt = 0; nt < 4; ++nt)
            Bf[nt].u = *(const uint4*)(wposg + (16 * nt + r) * 64 + 32 * ks + 8 * q);
#pragma unroll
        for (int mt = 0; mt < 4; ++mt)
#pragma unroll
            for (int nt = 0; nt < 4; ++nt)
                acc[mt][nt] = __builtin_amdgcn_mfma_f32_16x16x32_bf16(Af[mt].v, Bf[nt].v, acc[mt][nt], 0, 0, 0);
    }
    // twist: cols f=c+16nt (nt=0,1) pair with sin slots 32+f (nt+2) in SAME lane
#pragma unroll
    for (int mt = 0; mt < 4; ++mt) {
        uint2 t00 = *(const uint2*)(cslg + (c) * 64 + 16 * mt + 4 * q);       // cos, f=c
        uint2 t01 = *(const uint2*)(cslg + (32 + c) * 64 + 16 * mt + 4 * q);  // sin, f=c
        uint2 t10 = *(const uint2*)(cslg + (16 + c) * 64 + 16 * mt + 4 * q);  // cos, f=16+c
        uint2 t11 = *(const uint2*)(cslg + (48 + c) * 64 + 16 * mt + 4 * q);  // sin, f=16+c
#pragma unroll
        for (int i = 0; i < 4; ++i) {
            int l = 16 * mt + 4 * q + i;
            float cv0 = bfsel(t00, i), sv0 = bfsel(t01, i);
            float cv1 = bfsel(t10, i), sv1 = bfsel(t11, i);
            float pc0 = acc[mt][0][i], ps0 = acc[mt][2][i];
            float pc1 = acc[mt][1][i], ps1 = acc[mt][3][i];
            float u0 = pc0 * cv0 - ps0 * sv0;   // col c
            float u1 = pc1 * cv1 - ps1 * sv1;   // col 16+c
            float u2 = pc0 * sv0 + ps0 * cv0;   // col 32+c
            float u3 = pc1 * sv1 + ps1 * cv1;   // col 48+c
            packstore4(S1d + l * 36, c, u0, u1, u2, u3);
        }
    }

    // ---- prefetch V row (lane = m) while UW settles ----
    uint4 V4[8];
    {
        const uint4* vsrc = (const uint4*)(qkvb + (size_t)tk * 1536 + 1024 + h * 64);
#pragma unroll
        for (int j = 0; j < 8; ++j) V4[j] = vsrc[j];
    }

    // ---- GEMM3: bias = UW @ CST^T (A=S1, B=cst global) ----
#pragma unroll
    for (int mt = 0; mt < 4; ++mt)
#pragma unroll
        for (int nt = 0; nt < 4; ++nt) acc[mt][nt] = zf;
#pragma unroll
    for (int ks = 0; ks < 2; ++ks) {
        FragU Af[4], Bf[4];
#pragma unroll
        for (int mt = 0; mt < 4; ++mt)
            Af[mt].u = *(const uint4*)(S1d + (16 * mt + r) * 36 + 16 * ks + 4 * q);
#pragma unroll
        for (int nt = 0; nt < 4; ++nt)
            Bf[nt].u = *(const uint4*)(cstg + (16 * nt + r) * 64 + 32 * ks + 8 * q);
#pragma unroll
        for (int mt = 0; mt < 4; ++mt)
#pragma unroll
            for (int nt = 0; nt < 4; ++nt)
                acc[mt][nt] = __builtin_amdgcn_mfma_f32_16x16x32_bf16(Af[mt].v, Bf[nt].v, acc[mt][nt], 0, 0, 0);
    }
    // softmax over m per row l: final = SC + bias/62, masked -> -inf; ATTN -> S0
#pragma unroll
    for (int mt = 0; mt < 4; ++mt)
#pragma unroll
        for (int i = 0; i < 4; ++i) {
            int l = 16 * mt + 4 * q + i;
            float x[4];
#pragma unroll
            for (int nt = 0; nt < 4; ++nt) {
                unsigned u = S0d[l * 36 + 8 * nt + (c >> 1)];
                float scv = asf((c & 1) ? (u & 0xffff0000u) : (u << 16));
                x[nt] = mk[nt] ? -1e30f : fmaf(acc[mt][nt][i], 1.0f / 62.0f, scv);
            }
            float mx = fmaxf(fmaxf(x[0], x[1]), fmaxf(x[2], x[3]));
            mx = fmaxf(mx, __shfl_xor(mx, 1));
            mx = fmaxf(mx, __shfl_xor(mx, 2));
            mx = fmaxf(mx, __shfl_xor(mx, 4));
            mx = fmaxf(mx, __shfl_xor(mx, 8));
            float e0 = mk[0] ? 0.f : __expf(x[0] - mx);
            float e1 = mk[1] ? 0.f : __expf(x[1] - mx);
            float e2 = mk[2] ? 0.f : __expf(x[2] - mx);
            float e3 = mk[3] ? 0.f : __expf(x[3] - mx);
            float s = e0 + e1 + e2 + e3;
            s += __shfl_xor(s, 1);
            s += __shfl_xor(s, 2);
            s += __shfl_xor(s, 4);
            s += __shfl_xor(s, 8);
            float inv = 1.0f / s;
            packstore4(S0d + l * 36, c, e0 * inv, e1 * inv, e2 * inv, e3 * inv);
        }

    // ---- V^T scatter into S1 (UW dead): lane=m, xor-1 pack pairs ----
    {
        int odd = lane & 1;
        const unsigned* Vd = (const unsigned*)V4;
#pragma unroll
        for (int j = 0; j < 32; ++j) {
            unsigned my = Vd[j];
            unsigned pr = __shfl_xor(my, 1);
            unsigned val = odd ? ((pr >> 16) | (my & 0xffff0000u))
                               : ((my & 0xffffu) | (pr << 16));
            S1d[(2 * j + odd) * 36 + (lane >> 1)] = val;
        }
    }

    // ---- GEMM4: out = ATTN @ V (A=S0 rows l, B=S1 rows d) ----
#pragma unroll
    for (int mt = 0; mt < 4; ++mt)
#pragma unroll
        for (int nt = 0; nt < 4; ++nt) acc[mt][nt] = zf;
#pragma unroll
    for (int ks = 0; ks < 2; ++ks) {
        FragU Af[4], Bf[4];
#pragma unroll
        for (int mt = 0; mt < 4; ++mt)
            Af[mt].u = *(const uint4*)(S0d + (16 * mt + r) * 36 + 16 * ks + 4 * q);
#pragma unroll
        for (int nt = 0; nt < 4; ++nt)
            Bf[nt].u = *(const uint4*)(S1d + (16 * nt + r) * 36 + 16 * ks + 4 * q);
#pragma unroll
        for (int mt = 0; mt < 4; ++mt)
#pragma unroll
            for (int nt = 0; nt < 4; ++nt)
                acc[mt][nt] = __builtin_amdgcn_mfma_f32_16x16x32_bf16(Af[mt].v, Bf[nt].v, acc[mt][nt], 0, 0, 0);
    }
    // ---- LayerNorm over d (16-lane butterfly) + bf16 packed global write ----
    {
        unsigned* outw = (unsigned*)out_n;
        size_t hb = ((size_t)(b * 8 + h)) * 64;
#pragma unroll
        for (int mt = 0; mt < 4; ++mt)
#pragma unroll
            for (int i = 0; i < 4; ++i) {
                int l = 16 * mt + 4 * q + i;
                float v0 = acc[mt][0][i], v1 = acc[mt][1][i], v2 = acc[mt][2][i], v3 = acc[mt][3][i];
                float s1 = v0 + v1 + v2 + v3;
                float s2 = v0 * v0 + v1 * v1 + v2 * v2 + v3 * v3;
                s1 += __shfl_xor(s1, 1); s2 += __shfl_xor(s2, 1);
                s1 += __shfl_xor(s1, 2); s2 += __shfl_xor(s2, 2);
                s1 += __shfl_xor(s1, 4); s2 += __shfl_xor(s2, 4);
                s1 += __shfl_xor(s1, 8); s2 += __shfl_xor(s2, 8);
                float mu = s1 * (1.0f / 64.0f);
                float var = s2 * (1.0f / 64.0f) - mu * mu;
                float rstd = rsqrtf(var + 1e-5f);
                float y0 = (v0 - mu) * rstd * gv[0] + bvv[0];
                float y1 = (v1 - mu) * rstd * gv[1] + bvv[1];
                float y2 = (v2 - mu) * rstd * gv[2] + bvv[2];
                float y3 = (v3 - mu) * rstd * gv[3] + bvv[3];
                packstore4(outw + (hb + l) * 32, c, y0, y1, y2, y3);
            }
    }
}

// ---------------------------------------------------------------------------
// Kernel D: per b: h1 = relu(ft @ W1^T + b1), g[b,d,o] = sum_l w_l * h1
// ---------------------------------------------------------------------------
__global__ __launch_bounds__(256) void k_mlp(const int* __restrict__ inputs,
                                             const unsigned short* __restrict__ out_n,
                                             const float* __restrict__ W1,
                                             const float* __restrict__ b1,
                                             float* __restrict__ gws) {
    __shared__ float ft[8704];
    __shared__ float w1T[8][64];
    __shared__ float b1s[64];
    __shared__ float wl[64];
    int t = threadIdx.x;
    int b = blockIdx.x;
    if (t < 64) b1s[t] = b1[t];
    for (int e = t; e < 512; e += 256) {
        int o = e >> 3, hh = e & 7;
        w1T[hh][o] = W1[e];
    }
    if (t < 64) {
        int tok = inputs[b * 64 + t];
        unsigned long long bal = __ballot(tok != 0);
        int cnt = __popcll(bal);
        float Minv = (cnt > 0) ? (1.0f / (float)cnt) : 0.0f;
        wl[t] = (tok != 0) ? Minv : 0.0f;
    }
    float g4[4][4] = {};
    int d0 = (t >> 4) << 2, o0 = (t & 15) << 2;
    for (int lc = 0; lc < 4; ++lc) {
        __syncthreads();
        {
            int row = t >> 1, half = t & 1;
            int hh = row >> 4, l = row & 15;
            const uint4* src = (const uint4*)(out_n +
                ((((size_t)b * 8 + hh) * 64 + lc * 16 + l) * 64 + half * 32));
            float* dst = ft + (hh * 16 + l) * 68 + half * 32;
#pragma unroll
            for (int j = 0; j < 4; ++j) {
                uint4 u = src[j];
                dst[j * 8 + 0] = asf(u.x << 16); dst[j * 8 + 1] = asf(u.x & 0xffff0000u);
                dst[j * 8 + 2] = asf(u.y << 16); dst[j * 8 + 3] = asf(u.y & 0xffff0000u);
                dst[j * 8 + 4] = asf(u.z << 16); dst[j * 8 + 5] = asf(u.z & 0xffff0000u);
                dst[j * 8 + 6] = asf(u.w << 16); dst[j * 8 + 7] = asf(u.w & 0xffff0000u);
            }
        }
        __syncthreads();
        for (int l = 0; l < 16; ++l) {
            float pre[4][4];
#pragma unroll
            for (int j = 0; j < 4; ++j) {
                float bv = b1s[o0 + j];
                pre[0][j] = bv; pre[1][j] = bv; pre[2][j] = bv; pre[3][j] = bv;
            }
#pragma unroll
            for (int hh = 0; hh < 8; ++hh) {
                float4 av = *(const float4*)(ft + (hh * 16 + l) * 68 + d0);
                float4 wv = *(const float4*)(&w1T[hh][o0]);
                float aa[4] = {av.x, av.y, av.z, av.w};
                float ww[4] = {wv.x, wv.y, wv.z, wv.w};
#pragma unroll
                for (int i = 0; i < 4; ++i)
#pragma unroll
                    for (int j = 0; j < 4; ++j)
                        pre[i][j] = fmaf(aa[i], ww[j], pre[i][j]);
            }
            float w = wl[lc * 16 + l];
#pragma unroll
            for (int i = 0; i < 4; ++i)
#pragma unroll
                for (int j = 0; j < 4; ++j)
                    g4[i][j] = fmaf(w, fmaxf(pre[i][j], 0.0f), g4[i][j]);
        }
    }
#pragma unroll
    for (int i = 0; i < 4; ++i) {
        float4 o4 = make_float4(g4[i][0], g4[i][1], g4[i][2], g4[i][3]);
        *(float4*)(gws + ((size_t)b * 64 + d0 + i) * 64 + o0) = o4;
    }
}

// ---------------------------------------------------------------------------
// Kernel E: per name n: gbar = mean over 4 words; out = W2 @ gbar + b2
// ---------------------------------------------------------------------------
__global__ __launch_bounds__(256) void k_final(const float* __restrict__ gws,
                                               const float* __restrict__ W2,
                                               const float* __restrict__ b2,
                                               float* __restrict__ out) {
    __shared__ float gbar[4096];
    __shared__ float w2s[32 * 68];
    __shared__ float b2s[32];
    int t = threadIdx.x;
    int n = blockIdx.x;
    for (int e = t; e < 4096; e += 256) {
        size_t base = (size_t)(4 * n) * 4096 + e;
        gbar[e] = 0.25f * (gws[base] + gws[base + 4096] + gws[base + 8192] + gws[base + 12288]);
    }
    for (int e = t; e < 2048; e += 256) {
        int p = e >> 6, o = e & 63;
        w2s[p * 68 + o] = W2[e];
    }
    if (t < 32) b2s[t] = b2[t];
    __syncthreads();
#pragma unroll
    for (int jj = 0; jj < 8; ++jj) {
        int f = jj * 256 + t;
        int d = f >> 5, p = f & 31;
        float acc = b2s[p];
        for (int o4 = 0; o4 < 16; ++o4) {
            float4 gvv = *(const float4*)(gbar + d * 64 + o4 * 4);
            float4 wv = *(const float4*)(w2s + p * 68 + o4 * 4);
            acc = fmaf(gvv.x, wv.x, acc);
            acc = fmaf(gvv.y, wv.y, acc);
            acc = fmaf(gvv.z, wv.z, acc);
            acc = fmaf(gvv.w, wv.w, acc);
        }
        out[(size_t)n * 2048 + f] = acc;
    }
}

// ---------------------------------------------------------------------------
extern "C" void kernel_launch(void* const* d_in, const int* in_sizes, int n_in,
                              void* d_out, int out_size, void* d_ws, size_t ws_size,
                              hipStream_t stream) {
    const int*   inputs = (const int*)d_in[0];
    const float* W_emb  = (const float*)d_in[1];
    const float* W_qkv  = (const float*)d_in[2];
    const float* W_pos  = (const float*)d_in[3];
    const float* ln_g   = (const float*)d_in[4];
    const float* ln_b   = (const float*)d_in[5];
    const float* W1     = (const float*)d_in[6];
    const float* b1     = (const float*)d_in[7];
    const float* W2     = (const float*)d_in[8];
    const float* b2     = (const float*)d_in[9];
    float* out = (float*)d_out;

    // ws layout (u16 units unless noted): qkvb 6291456 | cst 4096 | csl 4096 |
    // wpos 4096 | gws fp32 8388608 | out_n u16 67108864
    unsigned short* qkvb = (unsigned short*)d_ws;
    unsigned short* cst  = qkvb + 6291456;
    unsigned short* csl  = cst + 4096;
    unsigned short* wpos = csl + 4096;
    float* gws = (float*)(wpos + 4096);
    unsigned short* out_n = (unsigned short*)(gws + 8388608);

    hipLaunchKernelGGL(k_qkv,   dim3(64 * 24), dim3(256), 0, stream, W_emb, W_qkv, qkvb);
    hipLaunchKernelGGL(k_tab,   dim3(1),       dim3(256), 0, stream, W_pos, cst, csl, wpos);
    hipLaunchKernelGGL(k_attn,  dim3(8192),    dim3(128), 0, stream,
                       inputs, qkvb, cst, csl, wpos, ln_g, ln_b, out_n);
    hipLaunchKernelGGL(k_mlp,   dim3(2048),    dim3(256), 0, stream, inputs, out_n, W1, b1, gws);
    hipLaunchKernelGGL(k_final, dim3(512),     dim3(256), 0, stream, gws, W2, b2, out);
}

// Round 3
// 494.604 us; speedup vs baseline: 2.3306x; 1.0241x over previous
//
#include <hip/hip_runtime.h>
#include <hip/hip_bf16.h>

// Problem constants: B=2048, L=64, V=4096, D=64, H=8, P=62

typedef __attribute__((ext_vector_type(8))) short short8;
typedef __attribute__((ext_vector_type(4))) float f32x4;

union FragU { uint4 u; short8 v; };

__device__ __forceinline__ unsigned short f2bf(float f) {
    union { float f; unsigned int i; } c; c.f = f;
    unsigned int i = c.i;
    unsigned int r = (i + 0x7fffu + ((i >> 16) & 1u)) >> 16;
    return (unsigned short)r;
}
__device__ __forceinline__ float asf(unsigned int u) {
    union { unsigned int i; float f; } c; c.i = u; return c.f;
}
__device__ __forceinline__ float bfsel(uint2 g, int i) {
    unsigned u = (i < 2) ? g.x : g.y;
    return asf((i & 1) ? (u & 0xffff0000u) : (u << 16));
}

// xor-1 lane-pair pack: lane holds val[nt] for col 16*nt+c of row `rowptr`.
__device__ __forceinline__ void packstore4(unsigned* rowptr, int c,
                                           float v0, float v1, float v2, float v3) {
    float p0 = __shfl_xor(v0, 1), p1 = __shfl_xor(v1, 1);
    float p2 = __shfl_xor(v2, 1), p3 = __shfl_xor(v3, 1);
    int odd = c & 1;
    unsigned a0 = odd ? ((unsigned)f2bf(p2) | ((unsigned)f2bf(v2) << 16))
                      : ((unsigned)f2bf(v0) | ((unsigned)f2bf(p0) << 16));
    unsigned a1 = odd ? ((unsigned)f2bf(p3) | ((unsigned)f2bf(v3) << 16))
                      : ((unsigned)f2bf(v1) | ((unsigned)f2bf(p1) << 16));
    int ba = (c >> 1) + (odd ? 16 : 0);
    rowptr[ba] = a0; rowptr[ba + 8] = a1;
}

// ---------------------------------------------------------------------------
// Kernel A: qkv table = W_emb (4096x64) @ W_qkv^T -> bf16 (4096x1536)
// ---------------------------------------------------------------------------
__global__ __launch_bounds__(256) void k_qkv(const float* __restrict__ W_emb,
                                             const float* __restrict__ W_qkv,
                                             unsigned short* __restrict__ qkvb) {
    __shared__ float At[4096];
    __shared__ float Bt[4096];
    int t = threadIdx.x;
    int bt = blockIdx.x / 24, rt = blockIdx.x - bt * 24;
    int r = t >> 2, part = t & 3;
    const float4* esrc = (const float4*)(W_emb + (size_t)((bt << 6) + r) * 64 + part * 16);
    const float4* wsrc = (const float4*)(W_qkv + (size_t)((rt << 6) + r) * 64 + part * 16);
#pragma unroll
    for (int j = 0; j < 4; ++j) {
        float4 e4 = esrc[j], w4 = wsrc[j];
        int c0 = part * 16 + j * 4;
        At[(c0 + 0) * 64 + r] = e4.x; At[(c0 + 1) * 64 + r] = e4.y;
        At[(c0 + 2) * 64 + r] = e4.z; At[(c0 + 3) * 64 + r] = e4.w;
        Bt[(c0 + 0) * 64 + r] = w4.x; Bt[(c0 + 1) * 64 + r] = w4.y;
        Bt[(c0 + 2) * 64 + r] = w4.z; Bt[(c0 + 3) * 64 + r] = w4.w;
    }
    __syncthreads();
    int l0 = (t >> 4) << 2, m0 = (t & 15) << 2;
    float acc[4][4] = {};
#pragma unroll 4
    for (int k = 0; k < 64; ++k) {
        float4 a  = *(const float4*)(At + k * 64 + l0);
        float4 bb = *(const float4*)(Bt + k * 64 + m0);
        float aa[4] = {a.x, a.y, a.z, a.w};
        float bv[4] = {bb.x, bb.y, bb.z, bb.w};
#pragma unroll
        for (int i = 0; i < 4; ++i)
#pragma unroll
            for (int j = 0; j < 4; ++j)
                acc[i][j] = fmaf(aa[i], bv[j], acc[i][j]);
    }
#pragma unroll
    for (int i = 0; i < 4; ++i) {
        unsigned w0 = (unsigned)f2bf(acc[i][0]) | ((unsigned)f2bf(acc[i][1]) << 16);
        unsigned w1 = (unsigned)f2bf(acc[i][2]) | ((unsigned)f2bf(acc[i][3]) << 16);
        unsigned* dst = (unsigned*)(qkvb + (size_t)((bt << 6) + l0 + i) * 1536 + (rt << 6) + m0);
        dst[0] = w0; dst[1] = w1;
    }
}

// ---------------------------------------------------------------------------
// Kernel B: trig + W_pos tables, padded 64-col layout
// ---------------------------------------------------------------------------
__global__ void k_tab(const float* __restrict__ W_pos,
                      unsigned short* __restrict__ cst,
                      unsigned short* __restrict__ csl,
                      unsigned short* __restrict__ wpos) {
    int t = threadIdx.x;
    const float w = 6.283185307179586f / 63.0f;
    for (int e = t; e < 4096; e += 256) {
        int row = e >> 6, col = e & 63;
        {
            int j = col, x = row;
            float val = 0.0f;
            if (j < 31)       val = cosf(w * (float)(((j + 1) * x) % 63));
            else if (j >= 32 && j < 63) val = sinf(w * (float)(((j - 31) * x) % 63));
            cst[e] = f2bf(val);
        }
        {
            int j = row, x = col;
            float val = 0.0f;
            if (j < 31)       val = cosf(w * (float)(((j + 1) * x) % 63));
            else if (j >= 32 && j < 63) val = sinf(w * (float)(((j - 31) * x) % 63));
            csl[e] = f2bf(val);
        }
        {
            int j = row;
            float val = 0.0f;
            if (j < 31) val = W_pos[j * 64 + col];
            else if (j >= 32 && j < 63) val = W_pos[(j - 1) * 64 + col];
            wpos[e] = f2bf(val);
        }
    }
}

// ---------------------------------------------------------------------------
// Kernel C: fused attention. Block = 2 waves = ONE (b,h) task; wave w2 owns
// row-half [32*w2, 32*w2+32). LDS 18432 B -> 8 blocks/CU (16 waves/CU).
//   S0: Q -> SC -> ATTN      S1: K -> UW -> V^T
// SC kept in registers across GEMM2/GEMM3 (C-layouts coincide).
// out written in [b][l][d][h] layout (u16 scatter) for k_mlp's MFMA B-frags.
// ---------------------------------------------------------------------------
__global__ __launch_bounds__(128, 4) void k_attn(
    const int* __restrict__ inputs,
    const unsigned short* __restrict__ qkvb,
    const unsigned short* __restrict__ cstg,
    const unsigned short* __restrict__ cslg,
    const unsigned short* __restrict__ wposg,
    const float* __restrict__ ln_g,
    const float* __restrict__ ln_b,
    unsigned short* __restrict__ out_t)
{
    __shared__ __align__(16) unsigned int smem[4608]; // 18432 B
    unsigned int* S0d = smem;
    unsigned int* S1d = smem + 2304;
    int t = threadIdx.x, w2 = t >> 6, lane = t & 63;
    int b = blockIdx.x >> 3, h = blockIdx.x & 7;
    const int* toks = inputs + b * 64;
    int r = lane & 15, q = lane >> 4, c = r;
    int tk = toks[lane];
    int mt0 = 2 * w2;

    int mk[4]; float gvv[4], bvv[4];
#pragma unroll
    for (int nt = 0; nt < 4; ++nt) {
        mk[nt] = (toks[16 * nt + c] == 0);
        gvv[nt] = ln_g[16 * nt + c];
        bvv[nt] = ln_b[16 * nt + c];
    }

    // ---- gather: wave0 -> Q into S0, wave1 -> K into S1 (lane = row) ----
    {
        const uint4* src = (const uint4*)(qkvb + (size_t)tk * 1536 + (w2 ? 512 : 0) + h * 64);
        uint4* dst = (uint4*)((w2 ? S1d : S0d) + lane * 36);
#pragma unroll
        for (int j = 0; j < 8; ++j) dst[j] = src[j];
    }
    __syncthreads(); // barrier 1

    f32x4 sc[2][4], acc[2][4];
    const f32x4 zf = {0.f, 0.f, 0.f, 0.f};

    // ---- GEMM1: sim = Q K^T (own 2 mt tiles x 4 nt) -> sc ----
#pragma unroll
    for (int u = 0; u < 2; ++u)
#pragma unroll
        for (int nt = 0; nt < 4; ++nt) sc[u][nt] = zf;
#pragma unroll
    for (int ks = 0; ks < 2; ++ks) {
        FragU Af[2], Bf[4];
#pragma unroll
        for (int u = 0; u < 2; ++u)
            Af[u].u = *(const uint4*)(S0d + (16 * (mt0 + u) + r) * 36 + 16 * ks + 4 * q);
#pragma unroll
        for (int nt = 0; nt < 4; ++nt)
            Bf[nt].u = *(const uint4*)(S1d + (16 * nt + r) * 36 + 16 * ks + 4 * q);
#pragma unroll
        for (int u = 0; u < 2; ++u)
#pragma unroll
            for (int nt = 0; nt < 4; ++nt)
                sc[u][nt] = __builtin_amdgcn_mfma_f32_16x16x32_bf16(Af[u].v, Bf[nt].v, sc[u][nt], 0, 0, 0);
    }
    // epilogue 1: scale+mask in regs (kept), pack bf16 SC -> S0 own rows
#pragma unroll
    for (int u = 0; u < 2; ++u) {
#pragma unroll
        for (int nt = 0; nt < 4; ++nt) {
            f32x4 vv = sc[u][nt];
#pragma unroll
            for (int i = 0; i < 4; ++i) vv[i] = mk[nt] ? 0.0f : vv[i] * 0.125f;
            sc[u][nt] = vv;
        }
#pragma unroll
        for (int i = 0; i < 4; ++i) {
            int l = 16 * (mt0 + u) + 4 * q + i;
            packstore4(S0d + l * 36, c, sc[u][0][i], sc[u][1][i], sc[u][2][i], sc[u][3][i]);
        }
    }
    __syncthreads(); // barrier 2: other wave's GEMM1 K-reads done before UW writes

    // ---- GEMM2: pos_w = SC @ Wpos^T + in-reg twist -> UW in S1 own rows ----
#pragma unroll
    for (int u = 0; u < 2; ++u)
#pragma unroll
        for (int nt = 0; nt < 4; ++nt) acc[u][nt] = zf;
#pragma unroll
    for (int ks = 0; ks < 2; ++ks) {
        FragU Af[2], Bf[4];
#pragma unroll
        for (int u = 0; u < 2; ++u)
            Af[u].u = *(const uint4*)(S0d + (16 * (mt0 + u) + r) * 36 + 16 * ks + 4 * q);
#pragma unroll
        for (int nt = 0; nt < 4; ++nt)
            Bf[nt].u = *(const uint4*)(wposg + (16 * nt + r) * 64 + 32 * ks + 8 * q);
#pragma unroll
        for (int u = 0; u < 2; ++u)
#pragma unroll
            for (int nt = 0; nt < 4; ++nt)
                acc[u][nt] = __builtin_amdgcn_mfma_f32_16x16x32_bf16(Af[u].v, Bf[nt].v, acc[u][nt], 0, 0, 0);
    }
#pragma unroll
    for (int u = 0; u < 2; ++u) {
        int mt = mt0 + u;
        uint2 t00 = *(const uint2*)(cslg + (c) * 64 + 16 * mt + 4 * q);
        uint2 t01 = *(const uint2*)(cslg + (32 + c) * 64 + 16 * mt + 4 * q);
        uint2 t10 = *(const uint2*)(cslg + (16 + c) * 64 + 16 * mt + 4 * q);
        uint2 t11 = *(const uint2*)(cslg + (48 + c) * 64 + 16 * mt + 4 * q);
#pragma unroll
        for (int i = 0; i < 4; ++i) {
            int l = 16 * mt + 4 * q + i;
            float cv0 = bfsel(t00, i), sv0 = bfsel(t01, i);
            float cv1 = bfsel(t10, i), sv1 = bfsel(t11, i);
            float pc0 = acc[u][0][i], ps0 = acc[u][2][i];
            float pc1 = acc[u][1][i], ps1 = acc[u][3][i];
            float u0 = pc0 * cv0 - ps0 * sv0;
            float u1 = pc1 * cv1 - ps1 * sv1;
            float u2 = pc0 * sv0 + ps0 * cv0;
            float u3 = pc1 * sv1 + ps1 * cv1;
            packstore4(S1d + l * 36, c, u0, u1, u2, u3);
        }
    }

    // ---- GEMM3: bias = UW @ CST^T (A = own UW rows, B = cst global) ----
#pragma unroll
    for (int u = 0; u < 2; ++u)
#pragma unroll
        for (int nt = 0; nt < 4; ++nt) acc[u][nt] = zf;
#pragma unroll
    for (int ks = 0; ks < 2; ++ks) {
        FragU Af[2], Bf[4];
#pragma unroll
        for (int u = 0; u < 2; ++u)
            Af[u].u = *(const uint4*)(S1d + (16 * (mt0 + u) + r) * 36 + 16 * ks + 4 * q);
#pragma unroll
        for (int nt = 0; nt < 4; ++nt)
            Bf[nt].u = *(const uint4*)(cstg + (16 * nt + r) * 64 + 32 * ks + 8 * q);
#pragma unroll
        for (int u = 0; u < 2; ++u)
#pragma unroll
            for (int nt = 0; nt < 4; ++nt)
                acc[u][nt] = __builtin_amdgcn_mfma_f32_16x16x32_bf16(Af[u].v, Bf[nt].v, acc[u][nt], 0, 0, 0);
    }

    // ---- prefetch V half-row (own d-half, 64 B per lane) ----
    uint4 V4[4];
    {
        const uint4* vsrc = (const uint4*)(qkvb + (size_t)tk * 1536 + 1024 + h * 64 + 32 * w2);
#pragma unroll
        for (int j = 0; j < 4; ++j) V4[j] = vsrc[j];
    }

    // ---- softmax: x = SC(regs) + bias/62; ATTN -> S0 own rows ----
#pragma unroll
    for (int u = 0; u < 2; ++u)
#pragma unroll
        for (int i = 0; i < 4; ++i) {
            int l = 16 * (mt0 + u) + 4 * q + i;
            float x0 = mk[0] ? -1e30f : fmaf(acc[u][0][i], 1.0f / 62.0f, sc[u][0][i]);
            float x1 = mk[1] ? -1e30f : fmaf(acc[u][1][i], 1.0f / 62.0f, sc[u][1][i]);
            float x2 = mk[2] ? -1e30f : fmaf(acc[u][2][i], 1.0f / 62.0f, sc[u][2][i]);
            float x3 = mk[3] ? -1e30f : fmaf(acc[u][3][i], 1.0f / 62.0f, sc[u][3][i]);
            float mx = fmaxf(fmaxf(x0, x1), fmaxf(x2, x3));
            mx = fmaxf(mx, __shfl_xor(mx, 1));
            mx = fmaxf(mx, __shfl_xor(mx, 2));
            mx = fmaxf(mx, __shfl_xor(mx, 4));
            mx = fmaxf(mx, __shfl_xor(mx, 8));
            float e0 = mk[0] ? 0.f : __expf(x0 - mx);
            float e1 = mk[1] ? 0.f : __expf(x1 - mx);
            float e2 = mk[2] ? 0.f : __expf(x2 - mx);
            float e3 = mk[3] ? 0.f : __expf(x3 - mx);
            float s = e0 + e1 + e2 + e3;
            s += __shfl_xor(s, 1);
            s += __shfl_xor(s, 2);
            s += __shfl_xor(s, 4);
            s += __shfl_xor(s, 8);
            float inv = 1.0f / s;
            packstore4(S0d + l * 36, c, e0 * inv, e1 * inv, e2 * inv, e3 * inv);
        }

    // ---- V^T scatter into S1 own d-half rows ----
    {
        int odd = lane & 1;
        const unsigned* Vd = (const unsigned*)V4;
#pragma unroll
        for (int jj = 0; jj < 16; ++jj) {
            unsigned my = Vd[jj];
            unsigned pr = __shfl_xor(my, 1);
            unsigned val = odd ? ((pr >> 16) | (my & 0xffff0000u))
                               : ((my & 0xffffu) | (pr << 16));
            S1d[(32 * w2 + 2 * jj + odd) * 36 + (lane >> 1)] = val;
        }
    }
    __syncthreads(); // barrier 3: V^T complete before GEMM4 B reads

    // ---- GEMM4: out = ATTN @ V ----
#pragma unroll
    for (int u = 0; u < 2; ++u)
#pragma unroll
        for (int nt = 0; nt < 4; ++nt) acc[u][nt] = zf;
#pragma unroll
    for (int ks = 0; ks < 2; ++ks) {
        FragU Af[2], Bf[4];
#pragma unroll
        for (int u = 0; u < 2; ++u)
            Af[u].u = *(const uint4*)(S0d + (16 * (mt0 + u) + r) * 36 + 16 * ks + 4 * q);
#pragma unroll
        for (int nt = 0; nt < 4; ++nt)
            Bf[nt].u = *(const uint4*)(S1d + (16 * nt + r) * 36 + 16 * ks + 4 * q);
#pragma unroll
        for (int u = 0; u < 2; ++u)
#pragma unroll
            for (int nt = 0; nt < 4; ++nt)
                acc[u][nt] = __builtin_amdgcn_mfma_f32_16x16x32_bf16(Af[u].v, Bf[nt].v, acc[u][nt], 0, 0, 0);
    }
    // ---- LayerNorm + u16 scatter store to out_t[b][l][d][h] ----
    {
        size_t ob = (size_t)b * 32768 + h;
#pragma unroll
        for (int u = 0; u < 2; ++u)
#pragma unroll
            for (int i = 0; i < 4; ++i) {
                int l = 16 * (mt0 + u) + 4 * q + i;
                float v0 = acc[u][0][i], v1 = acc[u][1][i], v2 = acc[u][2][i], v3 = acc[u][3][i];
                float s1 = v0 + v1 + v2 + v3;
                float s2 = v0 * v0 + v1 * v1 + v2 * v2 + v3 * v3;
                s1 += __shfl_xor(s1, 1); s2 += __shfl_xor(s2, 1);
                s1 += __shfl_xor(s1, 2); s2 += __shfl_xor(s2, 2);
                s1 += __shfl_xor(s1, 4); s2 += __shfl_xor(s2, 4);
                s1 += __shfl_xor(s1, 8); s2 += __shfl_xor(s2, 8);
                float mu = s1 * (1.0f / 64.0f);
                float var = s2 * (1.0f / 64.0f) - mu * mu;
                float rstd = rsqrtf(var + 1e-5f);
                size_t lb = ob + (size_t)l * 512;
                out_t[lb + (16 * 0 + c) * 8] = f2bf((v0 - mu) * rstd * gvv[0] + bvv[0]);
                out_t[lb + (16 * 1 + c) * 8] = f2bf((v1 - mu) * rstd * gvv[1] + bvv[1]);
                out_t[lb + (16 * 2 + c) * 8] = f2bf((v2 - mu) * rstd * gvv[2] + bvv[2]);
                out_t[lb + (16 * 3 + c) * 8] = f2bf((v3 - mu) * rstd * gvv[3] + bvv[3]);
            }
    }
}

// ---------------------------------------------------------------------------
// Kernel D (MFMA): per b: C_l[d][o] = X_l[d,h] @ W1^T (K=8 pad 32),
// g[b,d,o] = sum_l w_l * relu(C_l + b1). 4 waves = (ot,dt) quadrants.
// ---------------------------------------------------------------------------
__global__ __launch_bounds__(256) void k_mlp(const int* __restrict__ inputs,
                                             const unsigned short* __restrict__ out_t,
                                             const float* __restrict__ W1,
                                             const float* __restrict__ b1,
                                             float* __restrict__ gws) {
    __shared__ float wl[64];
    int t = threadIdx.x, w = t >> 6, lane = t & 63;
    int b = blockIdx.x;
    int ot = w >> 1, dt = w & 1;
    int kq = lane >> 4, n = lane & 15;

    if (t < 64) {
        int tok = inputs[b * 64 + t];
        unsigned long long bal = __ballot(tok != 0);
        int cnt = __popcll(bal);
        if (cnt < 1) cnt = 1;
        wl[t] = (tok != 0) ? 1.0f / (float)cnt : 0.0f;
    }

    // B-frags: W1 rows o = 32*ot + 16*om + n, k=h valid only for kq==0 lanes
    FragU Wf[2];
    float b1v[2];
#pragma unroll
    for (int om = 0; om < 2; ++om) {
        int o = 32 * ot + 16 * om + n;
        b1v[om] = b1[o];
        if (kq == 0) {
            const float4* wsrc = (const float4*)(W1 + o * 8);
            float4 wa = wsrc[0], wb = wsrc[1];
            Wf[om].u.x = (unsigned)f2bf(wa.x) | ((unsigned)f2bf(wa.y) << 16);
            Wf[om].u.y = (unsigned)f2bf(wa.z) | ((unsigned)f2bf(wa.w) << 16);
            Wf[om].u.z = (unsigned)f2bf(wb.x) | ((unsigned)f2bf(wb.y) << 16);
            Wf[om].u.w = (unsigned)f2bf(wb.z) | ((unsigned)f2bf(wb.w) << 16);
        } else {
            Wf[om].u = make_uint4(0, 0, 0, 0);
        }
    }
    __syncthreads();

    const unsigned short* Xb = out_t + (size_t)b * 32768;
    f32x4 racc[2][2];
    const f32x4 zf = {0.f, 0.f, 0.f, 0.f};
#pragma unroll
    for (int dm = 0; dm < 2; ++dm)
#pragma unroll
        for (int om = 0; om < 2; ++om) racc[dm][om] = zf;

    for (int l = 0; l < 64; ++l) {
        FragU Xf[2];
#pragma unroll
        for (int dm = 0; dm < 2; ++dm) {
            if (kq == 0)
                Xf[dm].u = *(const uint4*)(Xb + l * 512 + (32 * dt + 16 * dm + n) * 8);
            else
                Xf[dm].u = make_uint4(0, 0, 0, 0);
        }
        float wv = wl[l];
#pragma unroll
        for (int dm = 0; dm < 2; ++dm)
#pragma unroll
            for (int om = 0; om < 2; ++om) {
                f32x4 C = __builtin_amdgcn_mfma_f32_16x16x32_bf16(Xf[dm].v, Wf[om].v, zf, 0, 0, 0);
#pragma unroll
                for (int i = 0; i < 4; ++i)
                    racc[dm][om][i] = fmaf(wv, fmaxf(C[i] + b1v[om], 0.0f), racc[dm][om][i]);
            }
    }
    // store: row d = 32dt+16dm+4*kq+i, col o = 32ot+16om+n
    float* gb = gws + (size_t)b * 4096;
#pragma unroll
    for (int dm = 0; dm < 2; ++dm)
#pragma unroll
        for (int om = 0; om < 2; ++om) {
            int o = 32 * ot + 16 * om + n;
#pragma unroll
            for (int i = 0; i < 4; ++i) {
                int d = 32 * dt + 16 * dm + 4 * kq + i;
                gb[d * 64 + o] = racc[dm][om][i];
            }
        }
}

// ---------------------------------------------------------------------------
// Kernel E: per name n: gbar = mean over 4 words; out = W2 @ gbar + b2
// ---------------------------------------------------------------------------
__global__ __launch_bounds__(256) void k_final(const float* __restrict__ gws,
                                               const float* __restrict__ W2,
                                               const float* __restrict__ b2,
                                               float* __restrict__ out) {
    __shared__ float gbar[4096];
    __shared__ float w2s[32 * 68];
    __shared__ float b2s[32];
    int t = threadIdx.x;
    int n = blockIdx.x;
    for (int e = t; e < 4096; e += 256) {
        size_t base = (size_t)(4 * n) * 4096 + e;
        gbar[e] = 0.25f * (gws[base] + gws[base + 4096] + gws[base + 8192] + gws[base + 12288]);
    }
    for (int e = t; e < 2048; e += 256) {
        int p = e >> 6, o = e & 63;
        w2s[p * 68 + o] = W2[e];
    }
    if (t < 32) b2s[t] = b2[t];
    __syncthreads();
#pragma unroll
    for (int jj = 0; jj < 8; ++jj) {
        int f = jj * 256 + t;
        int d = f >> 5, p = f & 31;
        float acc = b2s[p];
        for (int o4 = 0; o4 < 16; ++o4) {
            float4 gvv = *(const float4*)(gbar + d * 64 + o4 * 4);
            float4 wv = *(const float4*)(w2s + p * 68 + o4 * 4);
            acc = fmaf(gvv.x, wv.x, acc);
            acc = fmaf(gvv.y, wv.y, acc);
            acc = fmaf(gvv.z, wv.z, acc);
            acc = fmaf(gvv.w, wv.w, acc);
        }
        out[(size_t)n * 2048 + f] = acc;
    }
}

// ---------------------------------------------------------------------------
extern "C" void kernel_launch(void* const* d_in, const int* in_sizes, int n_in,
                              void* d_out, int out_size, void* d_ws, size_t ws_size,
                              hipStream_t stream) {
    const int*   inputs = (const int*)d_in[0];
    const float* W_emb  = (const float*)d_in[1];
    const float* W_qkv  = (const float*)d_in[2];
    const float* W_pos  = (const float*)d_in[3];
    const float* ln_g   = (const float*)d_in[4];
    const float* ln_b   = (const float*)d_in[5];
    const float* W1     = (const float*)d_in[6];
    const float* b1     = (const float*)d_in[7];
    const float* W2     = (const float*)d_in[8];
    const float* b2     = (const float*)d_in[9];
    float* out = (float*)d_out;

    // ws layout (u16 units unless noted): qkvb 6291456 | cst 4096 | csl 4096 |
    // wpos 4096 | gws fp32 8388608 | out_t u16 67108864
    unsigned short* qkvb = (unsigned short*)d_ws;
    unsigned short* cst  = qkvb + 6291456;
    unsigned short* csl  = cst + 4096;
    unsigned short* wpos = csl + 4096;
    float* gws = (float*)(wpos + 4096);
    unsigned short* out_t = (unsigned short*)(gws + 8388608);

    hipLaunchKernelGGL(k_qkv,   dim3(64 * 24), dim3(256), 0, stream, W_emb, W_qkv, qkvb);
    hipLaunchKernelGGL(k_tab,   dim3(1),       dim3(256), 0, stream, W_pos, cst, csl, wpos);
    hipLaunchKernelGGL(k_attn,  dim3(16384),   dim3(128), 0, stream,
                       inputs, qkvb, cst, csl, wpos, ln_g, ln_b, out_t);
    hipLaunchKernelGGL(k_mlp,   dim3(2048),    dim3(256), 0, stream, inputs, out_t, W1, b1, gws);
    hipLaunchKernelGGL(k_final, dim3(512),     dim3(256), 0, stream, gws, W2, b2, out);
}

// Round 4
// 398.558 us; speedup vs baseline: 2.8923x; 1.2410x over previous
//
#include <hip/hip_runtime.h>
#include <hip/hip_bf16.h>

// Problem constants: B=2048, L=64, V=4096, D=64, H=8, P=62

typedef __attribute__((ext_vector_type(8))) short short8;
typedef __attribute__((ext_vector_type(4))) float f32x4;

union FragU { uint4 u; short8 v; };

__device__ __forceinline__ unsigned short f2bf(float f) {
    union { float f; unsigned int i; } c; c.f = f;
    unsigned int i = c.i;
    unsigned int r = (i + 0x7fffu + ((i >> 16) & 1u)) >> 16;
    return (unsigned short)r;
}
__device__ __forceinline__ float asf(unsigned int u) {
    union { unsigned int i; float f; } c; c.i = u; return c.f;
}
__device__ __forceinline__ float bfsel(uint2 g, int i) {
    unsigned u = (i < 2) ? g.x : g.y;
    return asf((i & 1) ? (u & 0xffff0000u) : (u << 16));
}

// xor-1 lane-pair pack: lane holds val[nt] for col 16*nt+c of row `rowptr`.
// Produces plain [col] u16 order across the 32-dword row.
__device__ __forceinline__ void packstore4(unsigned* rowptr, int c,
                                           float v0, float v1, float v2, float v3) {
    float p0 = __shfl_xor(v0, 1), p1 = __shfl_xor(v1, 1);
    float p2 = __shfl_xor(v2, 1), p3 = __shfl_xor(v3, 1);
    int odd = c & 1;
    unsigned a0 = odd ? ((unsigned)f2bf(p2) | ((unsigned)f2bf(v2) << 16))
                      : ((unsigned)f2bf(v0) | ((unsigned)f2bf(p0) << 16));
    unsigned a1 = odd ? ((unsigned)f2bf(p3) | ((unsigned)f2bf(v3) << 16))
                      : ((unsigned)f2bf(v1) | ((unsigned)f2bf(p1) << 16));
    int ba = (c >> 1) + (odd ? 16 : 0);
    rowptr[ba] = a0; rowptr[ba + 8] = a1;
}

// ---------------------------------------------------------------------------
// Kernel A: qkv table = W_emb (4096x64) @ W_qkv^T -> bf16 (4096x1536)
// ---------------------------------------------------------------------------
__global__ __launch_bounds__(256) void k_qkv(const float* __restrict__ W_emb,
                                             const float* __restrict__ W_qkv,
                                             unsigned short* __restrict__ qkvb) {
    __shared__ float At[4096];
    __shared__ float Bt[4096];
    int t = threadIdx.x;
    int bt = blockIdx.x / 24, rt = blockIdx.x - bt * 24;
    int r = t >> 2, part = t & 3;
    const float4* esrc = (const float4*)(W_emb + (size_t)((bt << 6) + r) * 64 + part * 16);
    const float4* wsrc = (const float4*)(W_qkv + (size_t)((rt << 6) + r) * 64 + part * 16);
#pragma unroll
    for (int j = 0; j < 4; ++j) {
        float4 e4 = esrc[j], w4 = wsrc[j];
        int c0 = part * 16 + j * 4;
        At[(c0 + 0) * 64 + r] = e4.x; At[(c0 + 1) * 64 + r] = e4.y;
        At[(c0 + 2) * 64 + r] = e4.z; At[(c0 + 3) * 64 + r] = e4.w;
        Bt[(c0 + 0) * 64 + r] = w4.x; Bt[(c0 + 1) * 64 + r] = w4.y;
        Bt[(c0 + 2) * 64 + r] = w4.z; Bt[(c0 + 3) * 64 + r] = w4.w;
    }
    __syncthreads();
    int l0 = (t >> 4) << 2, m0 = (t & 15) << 2;
    float acc[4][4] = {};
#pragma unroll 4
    for (int k = 0; k < 64; ++k) {
        float4 a  = *(const float4*)(At + k * 64 + l0);
        float4 bb = *(const float4*)(Bt + k * 64 + m0);
        float aa[4] = {a.x, a.y, a.z, a.w};
        float bv[4] = {bb.x, bb.y, bb.z, bb.w};
#pragma unroll
        for (int i = 0; i < 4; ++i)
#pragma unroll
            for (int j = 0; j < 4; ++j)
                acc[i][j] = fmaf(aa[i], bv[j], acc[i][j]);
    }
#pragma unroll
    for (int i = 0; i < 4; ++i) {
        unsigned w0 = (unsigned)f2bf(acc[i][0]) | ((unsigned)f2bf(acc[i][1]) << 16);
        unsigned w1 = (unsigned)f2bf(acc[i][2]) | ((unsigned)f2bf(acc[i][3]) << 16);
        unsigned* dst = (unsigned*)(qkvb + (size_t)((bt << 6) + l0 + i) * 1536 + (rt << 6) + m0);
        dst[0] = w0; dst[1] = w1;
    }
}

// ---------------------------------------------------------------------------
// Kernel B: trig + W_pos tables, padded 64-col layout
// ---------------------------------------------------------------------------
__global__ void k_tab(const float* __restrict__ W_pos,
                      unsigned short* __restrict__ cst,
                      unsigned short* __restrict__ csl,
                      unsigned short* __restrict__ wpos) {
    int t = threadIdx.x;
    const float w = 6.283185307179586f / 63.0f;
    for (int e = t; e < 4096; e += 256) {
        int row = e >> 6, col = e & 63;
        {
            int j = col, x = row;
            float val = 0.0f;
            if (j < 31)       val = cosf(w * (float)(((j + 1) * x) % 63));
            else if (j >= 32 && j < 63) val = sinf(w * (float)(((j - 31) * x) % 63));
            cst[e] = f2bf(val);
        }
        {
            int j = row, x = col;
            float val = 0.0f;
            if (j < 31)       val = cosf(w * (float)(((j + 1) * x) % 63));
            else if (j >= 32 && j < 63) val = sinf(w * (float)(((j - 31) * x) % 63));
            csl[e] = f2bf(val);
        }
        {
            int j = row;
            float val = 0.0f;
            if (j < 31) val = W_pos[j * 64 + col];
            else if (j >= 32 && j < 63) val = W_pos[(j - 1) * 64 + col];
            wpos[e] = f2bf(val);
        }
    }
}

// ---------------------------------------------------------------------------
// Kernel C: fused attention. Block = 2 waves = ONE (b,h) task; wave w2 owns
// row-half [32*w2, 32*w2+32). LDS 18432 B -> 8 blocks/CU.
//   S0: Q -> SC -> ATTN      S1: K -> UW -> V^T
// SC kept in registers across GEMM2/GEMM3. Softmax without max-subtraction
// (scores are O(1); masked keys -> -1e30 -> exp underflows to 0).
// Output: contiguous [b][h][l][d] bf16 rows (no cross-XCD line sharing).
// ---------------------------------------------------------------------------
__global__ __launch_bounds__(128, 4) void k_attn(
    const int* __restrict__ inputs,
    const unsigned short* __restrict__ qkvb,
    const unsigned short* __restrict__ cstg,
    const unsigned short* __restrict__ cslg,
    const unsigned short* __restrict__ wposg,
    const float* __restrict__ ln_g,
    const float* __restrict__ ln_b,
    unsigned short* __restrict__ out_n)
{
    __shared__ __align__(16) unsigned int smem[4608]; // 18432 B
    unsigned int* S0d = smem;
    unsigned int* S1d = smem + 2304;
    int t = threadIdx.x, w2 = t >> 6, lane = t & 63;
    int b = blockIdx.x >> 3, h = blockIdx.x & 7;
    const int* toks = inputs + b * 64;
    int r = lane & 15, q = lane >> 4, c = r;
    int tk = toks[lane];
    int mt0 = 2 * w2;

    int mk[4]; float gvv[4], bvv[4];
#pragma unroll
    for (int nt = 0; nt < 4; ++nt) {
        mk[nt] = (toks[16 * nt + c] == 0);
        gvv[nt] = ln_g[16 * nt + c];
        bvv[nt] = ln_b[16 * nt + c];
    }

    // ---- gather: wave0 -> Q into S0, wave1 -> K into S1 (lane = row) ----
    {
        const uint4* src = (const uint4*)(qkvb + (size_t)tk * 1536 + (w2 ? 512 : 0) + h * 64);
        uint4* dst = (uint4*)((w2 ? S1d : S0d) + lane * 36);
#pragma unroll
        for (int j = 0; j < 8; ++j) dst[j] = src[j];
    }
    __syncthreads(); // barrier 1

    f32x4 sc[2][4], acc[2][4];
    const f32x4 zf = {0.f, 0.f, 0.f, 0.f};

    // ---- GEMM1: sim = Q K^T ----
#pragma unroll
    for (int u = 0; u < 2; ++u)
#pragma unroll
        for (int nt = 0; nt < 4; ++nt) sc[u][nt] = zf;
#pragma unroll
    for (int ks = 0; ks < 2; ++ks) {
        FragU Af[2], Bf[4];
#pragma unroll
        for (int u = 0; u < 2; ++u)
            Af[u].u = *(const uint4*)(S0d + (16 * (mt0 + u) + r) * 36 + 16 * ks + 4 * q);
#pragma unroll
        for (int nt = 0; nt < 4; ++nt)
            Bf[nt].u = *(const uint4*)(S1d + (16 * nt + r) * 36 + 16 * ks + 4 * q);
#pragma unroll
        for (int u = 0; u < 2; ++u)
#pragma unroll
            for (int nt = 0; nt < 4; ++nt)
                sc[u][nt] = __builtin_amdgcn_mfma_f32_16x16x32_bf16(Af[u].v, Bf[nt].v, sc[u][nt], 0, 0, 0);
    }
    // epilogue 1: scale+mask in regs (kept), pack bf16 SC -> S0 own rows
#pragma unroll
    for (int u = 0; u < 2; ++u) {
#pragma unroll
        for (int nt = 0; nt < 4; ++nt) {
            f32x4 vv = sc[u][nt];
#pragma unroll
            for (int i = 0; i < 4; ++i) vv[i] = mk[nt] ? 0.0f : vv[i] * 0.125f;
            sc[u][nt] = vv;
        }
#pragma unroll
        for (int i = 0; i < 4; ++i) {
            int l = 16 * (mt0 + u) + 4 * q + i;
            packstore4(S0d + l * 36, c, sc[u][0][i], sc[u][1][i], sc[u][2][i], sc[u][3][i]);
        }
    }
    __syncthreads(); // barrier 2

    // ---- GEMM2: pos_w = SC @ Wpos^T + in-reg twist -> UW in S1 own rows ----
#pragma unroll
    for (int u = 0; u < 2; ++u)
#pragma unroll
        for (int nt = 0; nt < 4; ++nt) acc[u][nt] = zf;
#pragma unroll
    for (int ks = 0; ks < 2; ++ks) {
        FragU Af[2], Bf[4];
#pragma unroll
        for (int u = 0; u < 2; ++u)
            Af[u].u = *(const uint4*)(S0d + (16 * (mt0 + u) + r) * 36 + 16 * ks + 4 * q);
#pragma unroll
        for (int nt = 0; nt < 4; ++nt)
            Bf[nt].u = *(const uint4*)(wposg + (16 * nt + r) * 64 + 32 * ks + 8 * q);
#pragma unroll
        for (int u = 0; u < 2; ++u)
#pragma unroll
            for (int nt = 0; nt < 4; ++nt)
                acc[u][nt] = __builtin_amdgcn_mfma_f32_16x16x32_bf16(Af[u].v, Bf[nt].v, acc[u][nt], 0, 0, 0);
    }
#pragma unroll
    for (int u = 0; u < 2; ++u) {
        int mt = mt0 + u;
        uint2 t00 = *(const uint2*)(cslg + (c) * 64 + 16 * mt + 4 * q);
        uint2 t01 = *(const uint2*)(cslg + (32 + c) * 64 + 16 * mt + 4 * q);
        uint2 t10 = *(const uint2*)(cslg + (16 + c) * 64 + 16 * mt + 4 * q);
        uint2 t11 = *(const uint2*)(cslg + (48 + c) * 64 + 16 * mt + 4 * q);
#pragma unroll
        for (int i = 0; i < 4; ++i) {
            int l = 16 * mt + 4 * q + i;
            float cv0 = bfsel(t00, i), sv0 = bfsel(t01, i);
            float cv1 = bfsel(t10, i), sv1 = bfsel(t11, i);
            float pc0 = acc[u][0][i], ps0 = acc[u][2][i];
            float pc1 = acc[u][1][i], ps1 = acc[u][3][i];
            float u0 = pc0 * cv0 - ps0 * sv0;
            float u1 = pc1 * cv1 - ps1 * sv1;
            float u2 = pc0 * sv0 + ps0 * cv0;
            float u3 = pc1 * sv1 + ps1 * cv1;
            packstore4(S1d + l * 36, c, u0, u1, u2, u3);
        }
    }

    // ---- GEMM3: bias = UW @ CST^T ----
#pragma unroll
    for (int u = 0; u < 2; ++u)
#pragma unroll
        for (int nt = 0; nt < 4; ++nt) acc[u][nt] = zf;
#pragma unroll
    for (int ks = 0; ks < 2; ++ks) {
        FragU Af[2], Bf[4];
#pragma unroll
        for (int u = 0; u < 2; ++u)
            Af[u].u = *(const uint4*)(S1d + (16 * (mt0 + u) + r) * 36 + 16 * ks + 4 * q);
#pragma unroll
        for (int nt = 0; nt < 4; ++nt)
            Bf[nt].u = *(const uint4*)(cstg + (16 * nt + r) * 64 + 32 * ks + 8 * q);
#pragma unroll
        for (int u = 0; u < 2; ++u)
#pragma unroll
            for (int nt = 0; nt < 4; ++nt)
                acc[u][nt] = __builtin_amdgcn_mfma_f32_16x16x32_bf16(Af[u].v, Bf[nt].v, acc[u][nt], 0, 0, 0);
    }

    // ---- prefetch V half-row (own d-half, 64 B per lane) ----
    uint4 V4[4];
    {
        const uint4* vsrc = (const uint4*)(qkvb + (size_t)tk * 1536 + 1024 + h * 64 + 32 * w2);
#pragma unroll
        for (int j = 0; j < 4; ++j) V4[j] = vsrc[j];
    }

    // ---- softmax (no max pass): x = SC(regs) + bias/62; ATTN -> S0 ----
#pragma unroll
    for (int u = 0; u < 2; ++u)
#pragma unroll
        for (int i = 0; i < 4; ++i) {
            int l = 16 * (mt0 + u) + 4 * q + i;
            float e0 = mk[0] ? 0.f : __expf(fmaf(acc[u][0][i], 1.0f / 62.0f, sc[u][0][i]));
            float e1 = mk[1] ? 0.f : __expf(fmaf(acc[u][1][i], 1.0f / 62.0f, sc[u][1][i]));
            float e2 = mk[2] ? 0.f : __expf(fmaf(acc[u][2][i], 1.0f / 62.0f, sc[u][2][i]));
            float e3 = mk[3] ? 0.f : __expf(fmaf(acc[u][3][i], 1.0f / 62.0f, sc[u][3][i]));
            float s = e0 + e1 + e2 + e3;
            s += __shfl_xor(s, 1);
            s += __shfl_xor(s, 2);
            s += __shfl_xor(s, 4);
            s += __shfl_xor(s, 8);
            float inv = 1.0f / s;
            packstore4(S0d + l * 36, c, e0 * inv, e1 * inv, e2 * inv, e3 * inv);
        }

    // ---- V^T scatter into S1 own d-half rows ----
    {
        int odd = lane & 1;
        const unsigned* Vd = (const unsigned*)V4;
#pragma unroll
        for (int jj = 0; jj < 16; ++jj) {
            unsigned my = Vd[jj];
            unsigned pr = __shfl_xor(my, 1);
            unsigned val = odd ? ((pr >> 16) | (my & 0xffff0000u))
                               : ((my & 0xffffu) | (pr << 16));
            S1d[(32 * w2 + 2 * jj + odd) * 36 + (lane >> 1)] = val;
        }
    }
    __syncthreads(); // barrier 3

    // ---- GEMM4: out = ATTN @ V ----
#pragma unroll
    for (int u = 0; u < 2; ++u)
#pragma unroll
        for (int nt = 0; nt < 4; ++nt) acc[u][nt] = zf;
#pragma unroll
    for (int ks = 0; ks < 2; ++ks) {
        FragU Af[2], Bf[4];
#pragma unroll
        for (int u = 0; u < 2; ++u)
            Af[u].u = *(const uint4*)(S0d + (16 * (mt0 + u) + r) * 36 + 16 * ks + 4 * q);
#pragma unroll
        for (int nt = 0; nt < 4; ++nt)
            Bf[nt].u = *(const uint4*)(S1d + (16 * nt + r) * 36 + 16 * ks + 4 * q);
#pragma unroll
        for (int u = 0; u < 2; ++u)
#pragma unroll
            for (int nt = 0; nt < 4; ++nt)
                acc[u][nt] = __builtin_amdgcn_mfma_f32_16x16x32_bf16(Af[u].v, Bf[nt].v, acc[u][nt], 0, 0, 0);
    }
    // ---- LayerNorm + bf16 packed CONTIGUOUS write to out_n[b][h][l][d] ----
    {
        unsigned* outw = (unsigned*)out_n;
        size_t hb = ((size_t)b * 8 + h) * 64;
#pragma unroll
        for (int u = 0; u < 2; ++u)
#pragma unroll
            for (int i = 0; i < 4; ++i) {
                int l = 16 * (mt0 + u) + 4 * q + i;
                float v0 = acc[u][0][i], v1 = acc[u][1][i], v2 = acc[u][2][i], v3 = acc[u][3][i];
                float s1 = v0 + v1 + v2 + v3;
                float s2 = v0 * v0 + v1 * v1 + v2 * v2 + v3 * v3;
                s1 += __shfl_xor(s1, 1); s2 += __shfl_xor(s2, 1);
                s1 += __shfl_xor(s1, 2); s2 += __shfl_xor(s2, 2);
                s1 += __shfl_xor(s1, 4); s2 += __shfl_xor(s2, 4);
                s1 += __shfl_xor(s1, 8); s2 += __shfl_xor(s2, 8);
                float mu = s1 * (1.0f / 64.0f);
                float var = s2 * (1.0f / 64.0f) - mu * mu;
                float rstd = rsqrtf(var + 1e-5f);
                float y0 = (v0 - mu) * rstd * gvv[0] + bvv[0];
                float y1 = (v1 - mu) * rstd * gvv[1] + bvv[1];
                float y2 = (v2 - mu) * rstd * gvv[2] + bvv[2];
                float y3 = (v3 - mu) * rstd * gvv[3] + bvv[3];
                packstore4(outw + (hb + l) * 32, c, y0, y1, y2, y3);
            }
    }
}

// ---------------------------------------------------------------------------
// Kernel D (MFMA): per b. Stage 16-l chunks of out_n[b][h][l][d] into LDS
// transposed as XT[l][d][h] (pad 8), then C_l[d][o] = X_l[d,h] @ W1^T
// (K=8 pad 32); g[b,d,o] = sum_l w_l * relu(C_l + b1). 4 waves = quadrants.
// ---------------------------------------------------------------------------
__global__ __launch_bounds__(256) void k_mlp(const int* __restrict__ inputs,
                                             const unsigned short* __restrict__ out_n,
                                             const float* __restrict__ W1,
                                             const float* __restrict__ b1,
                                             float* __restrict__ gws) {
    __shared__ unsigned short XT[8320]; // 16 rows * 520 u16 (row pad 8)
    __shared__ float wl[64];
    int t = threadIdx.x, w = t >> 6, lane = t & 63;
    int b = blockIdx.x;
    int ot = w >> 1, dt = w & 1;
    int kq = lane >> 4, n = lane & 15;

    if (t < 64) {
        int tok = inputs[b * 64 + t];
        unsigned long long bal = __ballot(tok != 0);
        int cnt = __popcll(bal);
        if (cnt < 1) cnt = 1;
        wl[t] = (tok != 0) ? 1.0f / (float)cnt : 0.0f;
    }

    // B-frags: W1 rows o = 32*ot + 16*om + n, k=h valid only on kq==0 lanes
    FragU Wf[2];
    float b1v[2];
#pragma unroll
    for (int om = 0; om < 2; ++om) {
        int o = 32 * ot + 16 * om + n;
        b1v[om] = b1[o];
        if (kq == 0) {
            const float4* wsrc = (const float4*)(W1 + o * 8);
            float4 wa = wsrc[0], wb = wsrc[1];
            Wf[om].u.x = (unsigned)f2bf(wa.x) | ((unsigned)f2bf(wa.y) << 16);
            Wf[om].u.y = (unsigned)f2bf(wa.z) | ((unsigned)f2bf(wa.w) << 16);
            Wf[om].u.z = (unsigned)f2bf(wb.x) | ((unsigned)f2bf(wb.y) << 16);
            Wf[om].u.w = (unsigned)f2bf(wb.z) | ((unsigned)f2bf(wb.w) << 16);
        } else {
            Wf[om].u = make_uint4(0, 0, 0, 0);
        }
    }

    f32x4 racc[2][2];
    const f32x4 zf = {0.f, 0.f, 0.f, 0.f};
#pragma unroll
    for (int dm = 0; dm < 2; ++dm)
#pragma unroll
        for (int om = 0; om < 2; ++om) racc[dm][om] = zf;

    int lh = t & 7;          // h for the load phase
    int lr = (t >> 3) & 15;  // l-within-chunk
    int half = t >> 7;       // d half

    for (int cc = 0; cc < 4; ++cc) {
        __syncthreads(); // previous chunk's compute done before overwrite
        {
            const unsigned short* src = out_n + (size_t)b * 32768 + lh * 4096
                                        + (16 * cc + lr) * 64 + half * 32;
            unsigned short* dst = XT + lr * 520 + lh;
#pragma unroll
            for (int j = 0; j < 4; ++j) {
                uint4 u = ((const uint4*)src)[j];
                int d0 = half * 32 + j * 8;
                dst[(d0 + 0) * 8] = (unsigned short)(u.x & 0xffffu);
                dst[(d0 + 1) * 8] = (unsigned short)(u.x >> 16);
                dst[(d0 + 2) * 8] = (unsigned short)(u.y & 0xffffu);
                dst[(d0 + 3) * 8] = (unsigned short)(u.y >> 16);
                dst[(d0 + 4) * 8] = (unsigned short)(u.z & 0xffffu);
                dst[(d0 + 5) * 8] = (unsigned short)(u.z >> 16);
                dst[(d0 + 6) * 8] = (unsigned short)(u.w & 0xffffu);
                dst[(d0 + 7) * 8] = (unsigned short)(u.w >> 16);
            }
        }
        __syncthreads();
#pragma unroll 4
        for (int l = 0; l < 16; ++l) {
            FragU Xf[2];
#pragma unroll
            for (int dm = 0; dm < 2; ++dm) {
                if (kq == 0)
                    Xf[dm].u = *(const uint4*)(XT + l * 520 + (32 * dt + 16 * dm + n) * 8);
                else
                    Xf[dm].u = make_uint4(0, 0, 0, 0);
            }
            float wv = wl[16 * cc + l];
#pragma unroll
            for (int dm = 0; dm < 2; ++dm)
#pragma unroll
                for (int om = 0; om < 2; ++om) {
                    f32x4 C = __builtin_amdgcn_mfma_f32_16x16x32_bf16(Xf[dm].v, Wf[om].v, zf, 0, 0, 0);
#pragma unroll
                    for (int i = 0; i < 4; ++i)
                        racc[dm][om][i] = fmaf(wv, fmaxf(C[i] + b1v[om], 0.0f), racc[dm][om][i]);
                }
        }
    }
    // store: row d = 32dt+16dm+4*kq+i, col o = 32ot+16om+n
    float* gb = gws + (size_t)b * 4096;
#pragma unroll
    for (int dm = 0; dm < 2; ++dm)
#pragma unroll
        for (int om = 0; om < 2; ++om) {
            int o = 32 * ot + 16 * om + n;
#pragma unroll
            for (int i = 0; i < 4; ++i) {
                int d = 32 * dt + 16 * dm + 4 * kq + i;
                gb[d * 64 + o] = racc[dm][om][i];
            }
        }
}

// ---------------------------------------------------------------------------
// Kernel E: per name n: gbar = mean over 4 words; out = W2 @ gbar + b2
// ---------------------------------------------------------------------------
__global__ __launch_bounds__(256) void k_final(const float* __restrict__ gws,
                                               const float* __restrict__ W2,
                                               const float* __restrict__ b2,
                                               float* __restrict__ out) {
    __shared__ float gbar[4096];
    __shared__ float w2s[32 * 68];
    __shared__ float b2s[32];
    int t = threadIdx.x;
    int n = blockIdx.x;
    for (int e = t; e < 4096; e += 256) {
        size_t base = (size_t)(4 * n) * 4096 + e;
        gbar[e] = 0.25f * (gws[base] + gws[base + 4096] + gws[base + 8192] + gws[base + 12288]);
    }
    for (int e = t; e < 2048; e += 256) {
        int p = e >> 6, o = e & 63;
        w2s[p * 68 + o] = W2[e];
    }
    if (t < 32) b2s[t] = b2[t];
    __syncthreads();
#pragma unroll
    for (int jj = 0; jj < 8; ++jj) {
        int f = jj * 256 + t;
        int d = f >> 5, p = f & 31;
        float acc = b2s[p];
        for (int o4 = 0; o4 < 16; ++o4) {
            float4 gvv = *(const float4*)(gbar + d * 64 + o4 * 4);
            float4 wv = *(const float4*)(w2s + p * 68 + o4 * 4);
            acc = fmaf(gvv.x, wv.x, acc);
            acc = fmaf(gvv.y, wv.y, acc);
            acc = fmaf(gvv.z, wv.z, acc);
            acc = fmaf(gvv.w, wv.w, acc);
        }
        out[(size_t)n * 2048 + f] = acc;
    }
}

// ---------------------------------------------------------------------------
extern "C" void kernel_launch(void* const* d_in, const int* in_sizes, int n_in,
                              void* d_out, int out_size, void* d_ws, size_t ws_size,
                              hipStream_t stream) {
    const int*   inputs = (const int*)d_in[0];
    const float* W_emb  = (const float*)d_in[1];
    const float* W_qkv  = (const float*)d_in[2];
    const float* W_pos  = (const float*)d_in[3];
    const float* ln_g   = (const float*)d_in[4];
    const float* ln_b   = (const float*)d_in[5];
    const float* W1     = (const float*)d_in[6];
    const float* b1     = (const float*)d_in[7];
    const float* W2     = (const float*)d_in[8];
    const float* b2     = (const float*)d_in[9];
    float* out = (float*)d_out;

    // ws layout (u16 units unless noted): qkvb 6291456 | cst 4096 | csl 4096 |
    // wpos 4096 | gws fp32 8388608 | out_n u16 67108864
    unsigned short* qkvb = (unsigned short*)d_ws;
    unsigned short* cst  = qkvb + 6291456;
    unsigned short* csl  = cst + 4096;
    unsigned short* wpos = csl + 4096;
    float* gws = (float*)(wpos + 4096);
    unsigned short* out_n = (unsigned short*)(gws + 8388608);

    hipLaunchKernelGGL(k_qkv,   dim3(64 * 24), dim3(256), 0, stream, W_emb, W_qkv, qkvb);
    hipLaunchKernelGGL(k_tab,   dim3(1),       dim3(256), 0, stream, W_pos, cst, csl, wpos);
    hipLaunchKernelGGL(k_attn,  dim3(16384),   dim3(128), 0, stream,
                       inputs, qkvb, cst, csl, wpos, ln_g, ln_b, out_n);
    hipLaunchKernelGGL(k_mlp,   dim3(2048),    dim3(256), 0, stream, inputs, out_n, W1, b1, gws);
    hipLaunchKernelGGL(k_final, dim3(512),     dim3(256), 0, stream, gws, W2, b2, out);
}